// Round 16
// baseline (196.905 us; speedup 1.0000x reference)
//
#include <hip/hip_runtime.h>
#include <hip/hip_bf16.h>

#define NN 100000
#define DD 128
#define EE 500000
#define RR 3
#define MM (RR * NN)          // total buckets = 300000
#define NBIN 293              // ceil(MM / 1024) coarse bins
#define BCAP_RAW 6144         // per-bin raw capacity (Poisson mean 5120, +14 sigma)
#define BCAP_PAD 8192         // per-bin padded capacity (pad4: mean ~6700, ~18 sigma)

typedef __attribute__((ext_vector_type(8))) short   bf16x8;
typedef __attribute__((ext_vector_type(8))) ushort  ushort8;
typedef __attribute__((ext_vector_type(4))) float   f32x4;
typedef __attribute__((ext_vector_type(2))) unsigned uintx2;   // nt-load-compatible uint2

__device__ __forceinline__ ushort f2bf(float f) {
    __hip_bfloat16 h = __float2bfloat16(f);   // RNE
    return *(ushort*)&h;
}
__device__ __forceinline__ float bflo(unsigned v) {
    unsigned u = v << 16;
    return *(float*)&u;
}
__device__ __forceinline__ float bfhi(unsigned v) {
    unsigned u = v & 0xffff0000u;
    return *(float*)&u;
}

// ---- merged precompute: QBt (blk 0..511), P2t (512..639), cb (640), cursor-zero (641)
// QBt layout: [n=128][k=512]; k = s*128+i; s0 = Qx = sum_r Wr_r@P1_r, s1..3 = Wl_r@P1_r
__global__ __launch_bounds__(128) void precompute_kernel(
    const float* __restrict__ Wl, const float* __restrict__ Wr,
    const float* __restrict__ P1, const float* __restrict__ b1,
    const float* __restrict__ bl, const float* __restrict__ P2,
    ushort* __restrict__ QBt, ushort* __restrict__ P2t, float* __restrict__ cb,
    int* __restrict__ g_cursor)
{
    int blk = blockIdx.x;
    int j = threadIdx.x;
    if (blk < 4 * DD) {
        int s = blk >> 7;   // 0..3
        int i = blk & 127;  // k within segment
        float acc = 0.f;
        if (s == 0) {
            for (int r = 0; r < RR; ++r) {
                const float* wrow = Wr + (size_t)(r * DD + i) * DD;
                const float* pcol = P1 + (size_t)(r * DD) * DD + j;
                for (int k = 0; k < DD; ++k)
                    acc += wrow[k] * pcol[(size_t)k * DD];
            }
        } else {
            int r = s - 1;
            const float* wrow = Wl + (size_t)(r * DD + i) * DD;
            const float* pcol = P1 + (size_t)(r * DD) * DD + j;
            for (int k = 0; k < DD; ++k)
                acc += wrow[k] * pcol[(size_t)k * DD];
        }
        QBt[(size_t)j * 512 + s * DD + i] = f2bf(acc);
    } else if (blk < 4 * DD + DD) {
        int jj = blk - 4 * DD;   // output col
        P2t[(size_t)jj * DD + j] = f2bf(P2[(size_t)j * DD + jj]);
    } else if (blk == 4 * DD + DD) {
        float acc = b1[j];
        for (int r = 0; r < RR; ++r)
            for (int k = 0; k < DD; ++k)
                acc += bl[r * DD + k] * P1[(size_t)(r * DD + k) * DD + j];
        cb[j] = acc;
    } else {
        for (int i = j; i < NBIN; i += 128) g_cursor[i] = 0;
    }
}

// ---------------- x -> bf16 (last block also zeroes row NN) ----------------
__global__ __launch_bounds__(256) void x_tobf16_kernel(
    const float* __restrict__ x, ushort* __restrict__ xh)
{
    size_t i = (size_t)blockIdx.x * 256 + threadIdx.x;   // 4 elems each
    if (i * 4 >= (size_t)NN * DD) {
        if (i * 4 < (size_t)(NN + 1) * DD)
            ((uint2*)xh)[i] = make_uint2(0u, 0u);        // zero row NN
        return;
    }
    float4 v = ((const float4*)x)[i];
    unsigned lo = (unsigned)f2bf(v.x) | ((unsigned)f2bf(v.y) << 16);
    unsigned hi = (unsigned)f2bf(v.z) | ((unsigned)f2bf(v.w) << 16);
    ((uint2*)xh)[i] = make_uint2(lo, hi);
}

// ---------------- phase A: coarse binning (4096 edges/block) ----------------
// packed word = src | (local << 17);  src < 2^17, local < 2^10
__global__ __launch_bounds__(256) void bin_kernel(
    const int* __restrict__ e0, const int* __restrict__ e1, const int* __restrict__ e2,
    int* __restrict__ g_cursor, int* __restrict__ g_bindata)
{
    __shared__ int hist[NBIN];
    __shared__ int base[NBIN];
    int tid = threadIdx.x;
    for (int i = tid; i < NBIN; i += 256) hist[i] = 0;
    __syncthreads();
    int e_begin = blockIdx.x * 4096;
    int e_end = e_begin + 4096; if (e_end > RR * EE) e_end = RR * EE;
    // pass 1: histogram coarse bins (dst only)
    for (int i = e_begin + tid; i < e_end; i += 256) {
        int r = i / EE, e = i - r * EE;
        const int* ei = (r == 0) ? e0 : (r == 1) ? e1 : e2;
        int bin = (r * NN + ei[EE + e]) >> 10;
        atomicAdd(&hist[bin], 1);
    }
    __syncthreads();
    // reserve global space per bin, reset local cursors
    for (int i = tid; i < NBIN; i += 256) {
        int c = hist[i];
        base[i] = c ? atomicAdd(&g_cursor[i], c) : 0;
        hist[i] = 0;
    }
    __syncthreads();
    // pass 2: scatter packed words into bin segments (block-clustered)
    for (int i = e_begin + tid; i < e_end; i += 256) {
        int r = i / EE, e = i - r * EE;
        const int* ei = (r == 0) ? e0 : (r == 1) ? e1 : e2;
        int src = ei[e];
        int b = r * NN + ei[EE + e];
        int bin = b >> 10, local = b & 1023;
        int slot = base[bin] + atomicAdd(&hist[bin], 1);
        if (slot < BCAP_RAW) g_bindata[(size_t)bin * BCAP_RAW + slot] = src | (local << 17);
    }
}

// ---------------- phase B: per-bin local sort -> exact CSR, 4-padded ----------------
// bucket segments padded to multiple of 4 with src = NN (zero row of xh)
// meta[bucket] = {global start, raw deg}
__global__ __launch_bounds__(256) void sort_kernel(
    const int* __restrict__ g_cursor, const int* __restrict__ g_bindata,
    int* __restrict__ sorted, uint2* __restrict__ meta)
{
    __shared__ int hist[1024];
    __shared__ int start[1024];
    __shared__ int ssum[256];
    int bin = blockIdx.x, tid = threadIdx.x;
    int cnt = g_cursor[bin]; if (cnt > BCAP_RAW) cnt = BCAP_RAW;
    const int* bd = g_bindata + (size_t)bin * BCAP_RAW;
    for (int i = tid; i < 1024; i += 256) hist[i] = 0;
    __syncthreads();
    for (int i = tid; i < cnt; i += 256)
        atomicAdd(&hist[bd[i] >> 17], 1);
    __syncthreads();
    // exclusive scan over PADDED (mult-of-4) lengths (4 per thread + block scan)
    int t4 = tid * 4;
    int a0 = hist[t4], a1 = hist[t4 + 1], a2 = hist[t4 + 2], a3 = hist[t4 + 3];
    int p0 = (a0 + 3) & ~3, p1 = (a1 + 3) & ~3, p2 = (a2 + 3) & ~3, p3 = (a3 + 3) & ~3;
    int ts = p0 + p1 + p2 + p3;
    ssum[tid] = ts;
    __syncthreads();
    #pragma unroll
    for (int off = 1; off < 256; off <<= 1) {
        int tmp = (tid >= off) ? ssum[tid - off] : 0;
        __syncthreads();
        ssum[tid] += tmp;
        __syncthreads();
    }
    int ex = ssum[tid] - ts;
    start[t4] = ex; start[t4 + 1] = ex + p0;
    start[t4 + 2] = ex + p0 + p1; start[t4 + 3] = ex + p0 + p1 + p2;
    __syncthreads();
    // CSR meta (packed) + convert hist -> cursors
    for (int i = tid; i < 1024; i += 256) {
        int bucket = (bin << 10) + i;
        if (bucket < MM)
            meta[bucket] = make_uint2((unsigned)(bin * BCAP_PAD + start[i]),
                                      (unsigned)hist[i]);
        hist[i] = start[i];
    }
    __syncthreads();
    int* sb = sorted + (size_t)bin * BCAP_PAD;
    // scatter srcs bucket-contiguous (writes confined to L2-resident window)
    for (int i = tid; i < cnt; i += 256) {
        int w = bd[i];
        int pos = atomicAdd(&hist[w >> 17], 1);
        if (pos < BCAP_PAD) sb[pos] = w & 0x1ffff;
    }
    __syncthreads();
    // pad fill: positions [start+d, start+padlen) get zero-row index NN
    for (int i = tid; i < 1024; i += 256) {
        int s0 = start[i];
        int d = hist[i] - s0;              // final cursor - start = raw count
        int pl = (d + 3) & ~3;
        for (int p = s0 + d; p < s0 + pl; ++p)
            if (p < BCAP_PAD) sb[p] = NN;
    }
}

// ---------------- gather-aggregate: 8 buckets/wave, pad4, NT loads ----------------
// one meta round + one sidx preload covers 8 buckets (L<=64 for ~97% of groups).
__global__ __launch_bounds__(256) void aggregate_kernel(
    const ushort* __restrict__ xh, const int* __restrict__ sorted,
    const uint2* __restrict__ meta, ushort* __restrict__ aggh)
{
    int grp = blockIdx.x * 4 + (threadIdx.x >> 6);   // group of 8 buckets; grid = MM/32
    int lane = threadIdx.x & 63;
    int bid0 = grp * 8;                              // 8 consecutive buckets, same bin
    uintx2 m = __builtin_nontemporal_load(
        (const uintx2*)meta + (bid0 + (lane & 7)));  // one load round for all 8 metas
    int st[8], dg[8];
    #pragma unroll
    for (int b = 0; b < 8; ++b) {
        st[b] = __builtin_amdgcn_readlane((int)m.x, b);
        dg[b] = __builtin_amdgcn_readlane((int)m.y, b);
    }
    int start0 = st[0];
    int L = (st[7] - start0) + ((dg[7] + 3) & ~3);   // combined padded length (mean ~52)
    const unsigned* xu = (const unsigned*)xh;
    float ax[8], ay[8];
    #pragma unroll
    for (int b = 0; b < 8; ++b) { ax[b] = 0.f; ay[b] = 0.f; }

    if (L <= 64) {                                   // ~97% of groups
        int sidx = __builtin_nontemporal_load(&sorted[start0 + lane]);
        #pragma unroll
        for (int b = 0; b < 8; ++b) {
            int off = st[b] - start0;
            int degp = (dg[b] + 3) & ~3;
            for (int j = 0; j < degp; j += 4) {
                #pragma unroll
                for (int u = 0; u < 4; ++u) {
                    int sj = __builtin_amdgcn_readlane(sidx, off + j + u); // SGPR row idx
                    unsigned v = xu[(size_t)sj * 64 + lane];               // SGPR-base gather
                    ax[b] += bflo(v);
                    ay[b] += bfhi(v);
                }
            }
        }
    } else {                                         // fallback: uniform-addr loads
        #pragma unroll
        for (int b = 0; b < 8; ++b) {
            const int* sb = sorted + st[b];
            int degp = (dg[b] + 3) & ~3;
            for (int j = 0; j < degp; j += 4) {
                #pragma unroll
                for (int u = 0; u < 4; ++u) {
                    int sj = sb[j + u];              // padded: always valid
                    unsigned v = xu[(size_t)sj * 64 + lane];
                    ax[b] += bflo(v);
                    ay[b] += bfhi(v);
                }
            }
        }
    }
    #pragma unroll
    for (int b = 0; b < 8; ++b) {
        int deg = dg[b];
        float sc = 1.0f / (float)(deg > 1 ? deg : 1);
        unsigned o = (unsigned)f2bf(ax[b] * sc) | ((unsigned)f2bf(ay[b] * sc) << 16);
        ((unsigned*)(aggh + (size_t)(bid0 + b) * DD))[lane] = o;   // plain store: L3-warm
    }
}

// ---------------- fused GEMM: out = relu([xh|agg]@QBt^T + cb) @ P2t^T + b2 ----------
// Stage1: A-tile pipelined (prefetch chunk c+1 into regs during chunk c's MFMA);
//         B-fragments loaded DIRECTLY from L2-hot QBt (no LDS staging).
// Stage2: P2t frags in regs; Hs overlays As. LDS = 34,816 B -> 4 blocks/CU.
__global__ __launch_bounds__(256) void gemm_fused_kernel(
    const ushort* __restrict__ xh, const ushort* __restrict__ aggh,
    const ushort* __restrict__ QBt, const float* __restrict__ cb,
    const ushort* __restrict__ P2t, const float* __restrict__ b2,
    float* __restrict__ out)
{
    __shared__ ushort S[17408];                        // 34,816 B
    ushort (*As)[72]  = (ushort(*)[72])S;              // stage1 A  [128][72] (18,432 B)
    ushort (*Hs)[136] = (ushort(*)[136])S;             // stage2 A  [128][136] (overlays)

    int tid = threadIdx.x;
    int n0 = blockIdx.x * 128;
    int wid = tid >> 6;
    int lane = tid & 63;
    int wr = wid >> 1, wc = wid & 1;
    int lrow = lane & 15;
    int lk = (lane >> 4) * 8;

    f32x4 acc[4][4];
    #pragma unroll
    for (int i = 0; i < 4; ++i)
        #pragma unroll
        for (int j = 0; j < 4; ++j) acc[i][j] = (f32x4){0.f, 0.f, 0.f, 0.f};

    // per-thread A-staging coords: id covers 128 rows x 8 chunks of 16B
    ushort8 ra[4];
    auto loadA = [&](int c, ushort8* v) {
        int seg = c >> 1, kloc = (c & 1) * 64;
        const ushort* Abase = (seg == 0) ? xh : (aggh + (size_t)(seg - 1) * NN * DD);
        #pragma unroll
        for (int i = 0; i < 4; ++i) {
            int id = tid + i * 256;
            int row = id >> 3, s16 = id & 7;
            int grow = n0 + row;
            ushort8 t = {0, 0, 0, 0, 0, 0, 0, 0};
            if (grow < NN)
                t = *(const ushort8*)(Abase + (size_t)grow * DD + kloc + s16 * 8);
            v[i] = t;
        }
    };

    loadA(0, ra);

    for (int c = 0; c < 8; ++c) {
        if (c) __syncthreads();                // MFMA of c-1 done reading As
        #pragma unroll
        for (int i = 0; i < 4; ++i) {
            int id = tid + i * 256;
            int row = id >> 3, s16 = id & 7;
            *(ushort8*)&As[row][s16 * 8] = ra[i];
        }
        if (c < 7) loadA(c + 1, ra);           // issue early: lands during MFMA phase
        __syncthreads();
        #pragma unroll
        for (int ks = 0; ks < 2; ++ks) {
            bf16x8 a[4], b[4];
            #pragma unroll
            for (int ni = 0; ni < 4; ++ni)     // B direct from L2-hot QBt
                b[ni] = *(const bf16x8*)(QBt +
                    (size_t)(wc * 64 + ni * 16 + lrow) * 512 + c * 64 + ks * 32 + lk);
            #pragma unroll
            for (int mi = 0; mi < 4; ++mi)
                a[mi] = *(const bf16x8*)&As[wr * 64 + mi * 16 + lrow][ks * 32 + lk];
            #pragma unroll
            for (int mi = 0; mi < 4; ++mi)
                #pragma unroll
                for (int ni = 0; ni < 4; ++ni)
                    acc[mi][ni] = __builtin_amdgcn_mfma_f32_16x16x32_bf16(
                        a[mi], b[ni], acc[mi][ni], 0, 0, 0);
        }
    }

    __syncthreads();   // all stage1 LDS reads done before repurposing As as Hs

    // epilogue1: h = relu(acc + cb) -> Hs (bf16); C/D layout row=(lane>>4)*4+q, col=lane&15
    int crow = lane >> 4;
    int ccol = lane & 15;
    #pragma unroll
    for (int ni = 0; ni < 4; ++ni) {
        int gcol = wc * 64 + ni * 16 + ccol;
        float cv = cb[gcol];
        #pragma unroll
        for (int mi = 0; mi < 4; ++mi) {
            #pragma unroll
            for (int q = 0; q < 4; ++q) {
                float v = acc[mi][ni][q] + cv;
                v = v > 0.f ? v : 0.f;
                Hs[wr * 64 + mi * 16 + crow * 4 + q][gcol] = f2bf(v);
            }
        }
    }

    // stage2 B-fragments from global (L2-broadcast) — issue before the barrier
    bf16x8 pb[4][4];   // [ks][ni]
    #pragma unroll
    for (int ks = 0; ks < 4; ++ks)
        #pragma unroll
        for (int ni = 0; ni < 4; ++ni)
            pb[ks][ni] = *(const bf16x8*)(P2t +
                (size_t)(wc * 64 + ni * 16 + lrow) * DD + ks * 32 + lk);

    __syncthreads();

    f32x4 acc2[4][4];
    #pragma unroll
    for (int i = 0; i < 4; ++i)
        #pragma unroll
        for (int j = 0; j < 4; ++j) acc2[i][j] = (f32x4){0.f, 0.f, 0.f, 0.f};

    #pragma unroll
    for (int ks = 0; ks < 4; ++ks) {
        bf16x8 a[4];
        #pragma unroll
        for (int mi = 0; mi < 4; ++mi)
            a[mi] = *(const bf16x8*)&Hs[wr * 64 + mi * 16 + lrow][ks * 32 + lk];
        #pragma unroll
        for (int mi = 0; mi < 4; ++mi)
            #pragma unroll
            for (int ni = 0; ni < 4; ++ni)
                acc2[mi][ni] = __builtin_amdgcn_mfma_f32_16x16x32_bf16(
                    a[mi], pb[ks][ni], acc2[mi][ni], 0, 0, 0);
    }

    #pragma unroll
    for (int ni = 0; ni < 4; ++ni) {
        int gcol = wc * 64 + ni * 16 + ccol;
        float bv = b2[gcol];
        #pragma unroll
        for (int mi = 0; mi < 4; ++mi) {
            #pragma unroll
            for (int q = 0; q < 4; ++q) {
                int gr = n0 + wr * 64 + mi * 16 + crow * 4 + q;
                if (gr < NN)
                    __builtin_nontemporal_store(acc2[mi][ni][q] + bv,
                                                &out[(size_t)gr * DD + gcol]);
            }
        }
    }
}

extern "C" void kernel_launch(void* const* d_in, const int* in_sizes, int n_in,
                              void* d_out, int out_size, void* d_ws, size_t ws_size,
                              hipStream_t stream) {
    const float* x  = (const float*)d_in[0];
    const int*   e0 = (const int*)d_in[1];
    const int*   e1 = (const int*)d_in[2];
    const int*   e2 = (const int*)d_in[3];
    const float* Wl = (const float*)d_in[4];
    const float* bl = (const float*)d_in[5];
    const float* Wr = (const float*)d_in[6];
    const float* P1 = (const float*)d_in[7];
    const float* b1 = (const float*)d_in[8];
    const float* P2 = (const float*)d_in[9];
    const float* b2 = (const float*)d_in[10];
    float* out = (float*)d_out;

    // ws layout (~122 MB)
    ushort* xh       = (ushort*)d_ws;                     // (N+1)*D    (25.6 MB; row N = zeros)
    ushort* aggh     = xh + (size_t)(NN + 1) * DD;        // R*N*D      (76.8 MB)
    ushort* QBt      = aggh + (size_t)RR * NN * DD;       // 128*512
    ushort* P2t      = QBt + (size_t)128 * 512;           // 128*128
    float*  cb       = (float*)(P2t + (size_t)DD * DD);   // D
    int*    g_cursor = (int*)(cb + DD);                   // NBIN
    int*    g_bindat = g_cursor + NBIN;                   // NBIN*BCAP_RAW (7.2 MB)
    int*    sorted   = g_bindat + (size_t)NBIN * BCAP_RAW;// NBIN*BCAP_PAD + 64 slack (9.6 MB)
    uint2*  meta     = (uint2*)(sorted + (size_t)NBIN * BCAP_PAD + 64);  // MM uint2

    precompute_kernel<<<4 * DD + DD + 2, DD, 0, stream>>>(Wl, Wr, P1, b1, bl, P2,
                                                          QBt, P2t, cb, g_cursor);

    // grid covers (N+1)*D/4 uint2 slots: last block zeroes row NN
    x_tobf16_kernel<<<((NN + 1) * DD / 4 + 255) / 256, 256, 0, stream>>>(x, xh);

    int ablocks = (RR * EE + 4095) / 4096;   // 367
    bin_kernel<<<ablocks, 256, 0, stream>>>(e0, e1, e2, g_cursor, g_bindat);

    sort_kernel<<<NBIN, 256, 0, stream>>>(g_cursor, g_bindat, sorted, meta);

    aggregate_kernel<<<MM / 32, 256, 0, stream>>>(xh, sorted, meta, aggh);

    int gblocks = (NN + 127) / 128;
    gemm_fused_kernel<<<gblocks, 256, 0, stream>>>(xh, aggh, QBt, cb, P2t, b2, out);
}

// Round 17
// 188.584 us; speedup vs baseline: 1.0441x; 1.0441x over previous
//
#include <hip/hip_runtime.h>
#include <hip/hip_bf16.h>

#define NN 100000
#define DD 128
#define EE 500000
#define RR 3
#define MM (RR * NN)          // total buckets = 300000
#define NBIN 293              // ceil(MM / 1024) coarse bins
#define BCAP_RAW 6144         // per-bin raw capacity (Poisson mean 5120, +14 sigma)
#define BCAP_PAD 8192         // per-bin padded capacity (pad4: mean ~6700, ~18 sigma)

#define ABLOCKS 367           // (RR*EE + 4095)/4096  : bin chunks
#define TBLOCKS 12501         // ceil((NN+1)*DD/4 / 256) : tobf16 blocks
#define PBLOCKS 321           // ceil(641/2)           : precompute pairs

typedef __attribute__((ext_vector_type(8))) short   bf16x8;
typedef __attribute__((ext_vector_type(8))) ushort  ushort8;
typedef __attribute__((ext_vector_type(4))) float   f32x4;
typedef __attribute__((ext_vector_type(2))) unsigned uintx2;   // nt-load-compatible uint2

__device__ __forceinline__ ushort f2bf(float f) {
    __hip_bfloat16 h = __float2bfloat16(f);   // RNE
    return *(ushort*)&h;
}
__device__ __forceinline__ float bflo(unsigned v) {
    unsigned u = v << 16;
    return *(float*)&u;
}
__device__ __forceinline__ float bfhi(unsigned v) {
    unsigned u = v & 0xffff0000u;
    return *(float*)&u;
}

// ---------------- merged front-end: bin + x->bf16 + precompute ----------------
// blocks [0, ABLOCKS)                      : coarse edge binning
// blocks [ABLOCKS, ABLOCKS+TBLOCKS)        : x -> bf16 (+ zero row NN)
// blocks [ABLOCKS+TBLOCKS, +PBLOCKS)       : QBt / P2t / cb precompute (2 orig per block)
// All three regions are read/write-disjoint; g_cursor is pre-zeroed via memsetAsync.
__global__ __launch_bounds__(256) void prep_kernel(
    const int* __restrict__ e0, const int* __restrict__ e1, const int* __restrict__ e2,
    int* __restrict__ g_cursor, int* __restrict__ g_bindata,
    const float* __restrict__ x, ushort* __restrict__ xh,
    const float* __restrict__ Wl, const float* __restrict__ Wr,
    const float* __restrict__ P1, const float* __restrict__ b1,
    const float* __restrict__ bl, const float* __restrict__ P2,
    ushort* __restrict__ QBt, ushort* __restrict__ P2t, float* __restrict__ cb)
{
    __shared__ int hist[NBIN];
    __shared__ int base[NBIN];
    int blk = blockIdx.x;
    int tid = threadIdx.x;

    if (blk < ABLOCKS) {
        // ---- coarse binning: packed word = src | (local << 17) ----
        for (int i = tid; i < NBIN; i += 256) hist[i] = 0;
        __syncthreads();
        int e_begin = blk * 4096;
        int e_end = e_begin + 4096; if (e_end > RR * EE) e_end = RR * EE;
        for (int i = e_begin + tid; i < e_end; i += 256) {
            int r = i / EE, e = i - r * EE;
            const int* ei = (r == 0) ? e0 : (r == 1) ? e1 : e2;
            int bin = (r * NN + ei[EE + e]) >> 10;
            atomicAdd(&hist[bin], 1);
        }
        __syncthreads();
        for (int i = tid; i < NBIN; i += 256) {
            int c = hist[i];
            base[i] = c ? atomicAdd(&g_cursor[i], c) : 0;
            hist[i] = 0;
        }
        __syncthreads();
        for (int i = e_begin + tid; i < e_end; i += 256) {
            int r = i / EE, e = i - r * EE;
            const int* ei = (r == 0) ? e0 : (r == 1) ? e1 : e2;
            int src = ei[e];
            int b = r * NN + ei[EE + e];
            int bin = b >> 10, local = b & 1023;
            int slot = base[bin] + atomicAdd(&hist[bin], 1);
            if (slot < BCAP_RAW)
                g_bindata[(size_t)bin * BCAP_RAW + slot] = src | (local << 17);
        }
    } else if (blk < ABLOCKS + TBLOCKS) {
        // ---- x -> bf16 (4 elems/thread); tail zeroes row NN ----
        size_t i = (size_t)(blk - ABLOCKS) * 256 + tid;
        if (i * 4 >= (size_t)NN * DD) {
            if (i * 4 < (size_t)(NN + 1) * DD)
                ((uint2*)xh)[i] = make_uint2(0u, 0u);
            return;
        }
        float4 v = ((const float4*)x)[i];
        unsigned lo = (unsigned)f2bf(v.x) | ((unsigned)f2bf(v.y) << 16);
        unsigned hi = (unsigned)f2bf(v.z) | ((unsigned)f2bf(v.w) << 16);
        ((uint2*)xh)[i] = make_uint2(lo, hi);
    } else {
        // ---- precompute: 2 original 128-thread blocks per physical block ----
        int orig = (blk - ABLOCKS - TBLOCKS) * 2 + (tid >> 7);
        int j = tid & 127;
        if (orig >= 641) return;
        if (orig < 4 * DD) {
            int s = orig >> 7;   // 0..3
            int i = orig & 127;  // k within segment
            float acc = 0.f;
            if (s == 0) {
                for (int r = 0; r < RR; ++r) {
                    const float* wrow = Wr + (size_t)(r * DD + i) * DD;
                    const float* pcol = P1 + (size_t)(r * DD) * DD + j;
                    for (int k = 0; k < DD; ++k)
                        acc += wrow[k] * pcol[(size_t)k * DD];
                }
            } else {
                int r = s - 1;
                const float* wrow = Wl + (size_t)(r * DD + i) * DD;
                const float* pcol = P1 + (size_t)(r * DD) * DD + j;
                for (int k = 0; k < DD; ++k)
                    acc += wrow[k] * pcol[(size_t)k * DD];
            }
            QBt[(size_t)j * 512 + s * DD + i] = f2bf(acc);
        } else if (orig < 4 * DD + DD) {
            int jj = orig - 4 * DD;   // output col
            P2t[(size_t)jj * DD + j] = f2bf(P2[(size_t)j * DD + jj]);
        } else {
            float acc = b1[j];
            for (int r = 0; r < RR; ++r)
                for (int k = 0; k < DD; ++k)
                    acc += bl[r * DD + k] * P1[(size_t)(r * DD + k) * DD + j];
            cb[j] = acc;
        }
    }
}

// ---------------- phase B: per-bin local sort -> exact CSR, 4-padded ----------------
// bucket segments padded to multiple of 4 with src = NN (zero row of xh)
// meta[bucket] = {global start, raw deg}
__global__ __launch_bounds__(256) void sort_kernel(
    const int* __restrict__ g_cursor, const int* __restrict__ g_bindata,
    int* __restrict__ sorted, uint2* __restrict__ meta)
{
    __shared__ int hist[1024];
    __shared__ int start[1024];
    __shared__ int ssum[256];
    int bin = blockIdx.x, tid = threadIdx.x;
    int cnt = g_cursor[bin]; if (cnt > BCAP_RAW) cnt = BCAP_RAW;
    const int* bd = g_bindata + (size_t)bin * BCAP_RAW;
    for (int i = tid; i < 1024; i += 256) hist[i] = 0;
    __syncthreads();
    for (int i = tid; i < cnt; i += 256)
        atomicAdd(&hist[bd[i] >> 17], 1);
    __syncthreads();
    // exclusive scan over PADDED (mult-of-4) lengths (4 per thread + block scan)
    int t4 = tid * 4;
    int a0 = hist[t4], a1 = hist[t4 + 1], a2 = hist[t4 + 2], a3 = hist[t4 + 3];
    int p0 = (a0 + 3) & ~3, p1 = (a1 + 3) & ~3, p2 = (a2 + 3) & ~3, p3 = (a3 + 3) & ~3;
    int ts = p0 + p1 + p2 + p3;
    ssum[tid] = ts;
    __syncthreads();
    #pragma unroll
    for (int off = 1; off < 256; off <<= 1) {
        int tmp = (tid >= off) ? ssum[tid - off] : 0;
        __syncthreads();
        ssum[tid] += tmp;
        __syncthreads();
    }
    int ex = ssum[tid] - ts;
    start[t4] = ex; start[t4 + 1] = ex + p0;
    start[t4 + 2] = ex + p0 + p1; start[t4 + 3] = ex + p0 + p1 + p2;
    __syncthreads();
    // CSR meta (packed) + convert hist -> cursors
    for (int i = tid; i < 1024; i += 256) {
        int bucket = (bin << 10) + i;
        if (bucket < MM)
            meta[bucket] = make_uint2((unsigned)(bin * BCAP_PAD + start[i]),
                                      (unsigned)hist[i]);
        hist[i] = start[i];
    }
    __syncthreads();
    int* sb = sorted + (size_t)bin * BCAP_PAD;
    // scatter srcs bucket-contiguous (writes confined to L2-resident window)
    for (int i = tid; i < cnt; i += 256) {
        int w = bd[i];
        int pos = atomicAdd(&hist[w >> 17], 1);
        if (pos < BCAP_PAD) sb[pos] = w & 0x1ffff;
    }
    __syncthreads();
    // pad fill: positions [start+d, start+padlen) get zero-row index NN
    for (int i = tid; i < 1024; i += 256) {
        int s0 = start[i];
        int d = hist[i] - s0;              // final cursor - start = raw count
        int pl = (d + 3) & ~3;
        for (int p = s0 + d; p < s0 + pl; ++p)
            if (p < BCAP_PAD) sb[p] = NN;
    }
}

// ---------------- gather-aggregate: 8 buckets/wave, pad4, NT loads ----------------
// one meta round + one sidx preload covers 8 buckets (L<=64 for ~97% of groups).
__global__ __launch_bounds__(256) void aggregate_kernel(
    const ushort* __restrict__ xh, const int* __restrict__ sorted,
    const uint2* __restrict__ meta, ushort* __restrict__ aggh)
{
    int grp = blockIdx.x * 4 + (threadIdx.x >> 6);   // group of 8 buckets; grid = MM/32
    int lane = threadIdx.x & 63;
    int bid0 = grp * 8;                              // 8 consecutive buckets, same bin
    uintx2 m = __builtin_nontemporal_load(
        (const uintx2*)meta + (bid0 + (lane & 7)));  // one load round for all 8 metas
    int st[8], dg[8];
    #pragma unroll
    for (int b = 0; b < 8; ++b) {
        st[b] = __builtin_amdgcn_readlane((int)m.x, b);
        dg[b] = __builtin_amdgcn_readlane((int)m.y, b);
    }
    int start0 = st[0];
    int L = (st[7] - start0) + ((dg[7] + 3) & ~3);   // combined padded length (mean ~52)
    const unsigned* xu = (const unsigned*)xh;
    float ax[8], ay[8];
    #pragma unroll
    for (int b = 0; b < 8; ++b) { ax[b] = 0.f; ay[b] = 0.f; }

    if (L <= 64) {                                   // ~97% of groups
        int sidx = __builtin_nontemporal_load(&sorted[start0 + lane]);
        #pragma unroll
        for (int b = 0; b < 8; ++b) {
            int off = st[b] - start0;
            int degp = (dg[b] + 3) & ~3;
            for (int j = 0; j < degp; j += 4) {
                #pragma unroll
                for (int u = 0; u < 4; ++u) {
                    int sj = __builtin_amdgcn_readlane(sidx, off + j + u); // SGPR row idx
                    unsigned v = xu[(size_t)sj * 64 + lane];               // SGPR-base gather
                    ax[b] += bflo(v);
                    ay[b] += bfhi(v);
                }
            }
        }
    } else {                                         // fallback: uniform-addr loads
        #pragma unroll
        for (int b = 0; b < 8; ++b) {
            const int* sb = sorted + st[b];
            int degp = (dg[b] + 3) & ~3;
            for (int j = 0; j < degp; j += 4) {
                #pragma unroll
                for (int u = 0; u < 4; ++u) {
                    int sj = sb[j + u];              // padded: always valid
                    unsigned v = xu[(size_t)sj * 64 + lane];
                    ax[b] += bflo(v);
                    ay[b] += bfhi(v);
                }
            }
        }
    }
    #pragma unroll
    for (int b = 0; b < 8; ++b) {
        int deg = dg[b];
        float sc = 1.0f / (float)(deg > 1 ? deg : 1);
        unsigned o = (unsigned)f2bf(ax[b] * sc) | ((unsigned)f2bf(ay[b] * sc) << 16);
        ((unsigned*)(aggh + (size_t)(bid0 + b) * DD))[lane] = o;   // plain store: L3-warm
    }
}

// ---------------- fused GEMM: out = relu([xh|agg]@QBt^T + cb) @ P2t^T + b2 ----------
// (R15 known-good version) Stage1: 128x128 h-tile via 8 K-chunks, As/Bs in LDS.
// Stage2: P2t B-fragments in REGISTERS; Hs overlays As/Bs. LDS = 36,864 B.
__global__ __launch_bounds__(256) void gemm_fused_kernel(
    const ushort* __restrict__ xh, const ushort* __restrict__ aggh,
    const ushort* __restrict__ QBt, const float* __restrict__ cb,
    const ushort* __restrict__ P2t, const float* __restrict__ b2,
    float* __restrict__ out)
{
    __shared__ ushort S[18432];                        // 36,864 B
    ushort (*As)[72]  = (ushort(*)[72])S;              // stage1 A  [128][72]
    ushort (*Bs)[72]  = (ushort(*)[72])(S + 9216);     // stage1 B  [128][72]
    ushort (*Hs)[136] = (ushort(*)[136])S;             // stage2 A  [128][136] (overlays)

    int tid = threadIdx.x;
    int n0 = blockIdx.x * 128;
    int wid = tid >> 6;
    int lane = tid & 63;
    int wr = wid >> 1, wc = wid & 1;
    int lrow = lane & 15;
    int lk = (lane >> 4) * 8;

    f32x4 acc[4][4];
    #pragma unroll
    for (int i = 0; i < 4; ++i)
        #pragma unroll
        for (int j = 0; j < 4; ++j) acc[i][j] = (f32x4){0.f, 0.f, 0.f, 0.f};

    for (int c = 0; c < 8; ++c) {
        int seg = c >> 1;
        int kloc = (c & 1) * 64;
        const ushort* Abase = (seg == 0) ? xh : (aggh + (size_t)(seg - 1) * NN * DD);
        if (c) __syncthreads();
        #pragma unroll
        for (int i = 0; i < 4; ++i) {
            int id = tid + i * 256;
            int row = id >> 3;
            int s16 = id & 7;
            int grow = n0 + row;
            ushort8 v = {0, 0, 0, 0, 0, 0, 0, 0};
            if (grow < NN)
                v = *(const ushort8*)(Abase + (size_t)grow * DD + kloc + s16 * 8);
            *(ushort8*)&As[row][s16 * 8] = v;
        }
        #pragma unroll
        for (int i = 0; i < 4; ++i) {
            int id = tid + i * 256;
            int n = id >> 3;
            int s16 = id & 7;
            *(ushort8*)&Bs[n][s16 * 8] =
                *(const ushort8*)(QBt + (size_t)n * 512 + c * 64 + s16 * 8);
        }
        __syncthreads();
        #pragma unroll
        for (int ks = 0; ks < 2; ++ks) {
            bf16x8 a[4], b[4];
            #pragma unroll
            for (int mi = 0; mi < 4; ++mi)
                a[mi] = *(const bf16x8*)&As[wr * 64 + mi * 16 + lrow][ks * 32 + lk];
            #pragma unroll
            for (int ni = 0; ni < 4; ++ni)
                b[ni] = *(const bf16x8*)&Bs[wc * 64 + ni * 16 + lrow][ks * 32 + lk];
            #pragma unroll
            for (int mi = 0; mi < 4; ++mi)
                #pragma unroll
                for (int ni = 0; ni < 4; ++ni)
                    acc[mi][ni] = __builtin_amdgcn_mfma_f32_16x16x32_bf16(
                        a[mi], b[ni], acc[mi][ni], 0, 0, 0);
        }
    }

    // stage2 B-fragments from global (L2-broadcast) — issue BEFORE the barrier so
    // the ~200cy L2 latency hides under the sync + Hs writes.
    bf16x8 pb[4][4];   // [ks][ni]
    #pragma unroll
    for (int ks = 0; ks < 4; ++ks)
        #pragma unroll
        for (int ni = 0; ni < 4; ++ni)
            pb[ks][ni] = *(const bf16x8*)(P2t +
                (size_t)(wc * 64 + ni * 16 + lrow) * DD + ks * 32 + lk);

    __syncthreads();   // all stage1 LDS reads done before repurposing as Hs

    // epilogue1: h = relu(acc + cb) -> Hs (bf16); C/D layout row=(lane>>4)*4+q, col=lane&15
    int crow = lane >> 4;
    int ccol = lane & 15;
    #pragma unroll
    for (int ni = 0; ni < 4; ++ni) {
        int gcol = wc * 64 + ni * 16 + ccol;
        float cv = cb[gcol];
        #pragma unroll
        for (int mi = 0; mi < 4; ++mi) {
            #pragma unroll
            for (int q = 0; q < 4; ++q) {
                float v = acc[mi][ni][q] + cv;
                v = v > 0.f ? v : 0.f;
                Hs[wr * 64 + mi * 16 + crow * 4 + q][gcol] = f2bf(v);
            }
        }
    }
    __syncthreads();

    f32x4 acc2[4][4];
    #pragma unroll
    for (int i = 0; i < 4; ++i)
        #pragma unroll
        for (int j = 0; j < 4; ++j) acc2[i][j] = (f32x4){0.f, 0.f, 0.f, 0.f};

    #pragma unroll
    for (int ks = 0; ks < 4; ++ks) {
        bf16x8 a[4];
        #pragma unroll
        for (int mi = 0; mi < 4; ++mi)
            a[mi] = *(const bf16x8*)&Hs[wr * 64 + mi * 16 + lrow][ks * 32 + lk];
        #pragma unroll
        for (int mi = 0; mi < 4; ++mi)
            #pragma unroll
            for (int ni = 0; ni < 4; ++ni)
                acc2[mi][ni] = __builtin_amdgcn_mfma_f32_16x16x32_bf16(
                    a[mi], pb[ks][ni], acc2[mi][ni], 0, 0, 0);
    }

    #pragma unroll
    for (int ni = 0; ni < 4; ++ni) {
        int gcol = wc * 64 + ni * 16 + ccol;
        float bv = b2[gcol];
        #pragma unroll
        for (int mi = 0; mi < 4; ++mi) {
            #pragma unroll
            for (int q = 0; q < 4; ++q) {
                int gr = n0 + wr * 64 + mi * 16 + crow * 4 + q;
                if (gr < NN)
                    __builtin_nontemporal_store(acc2[mi][ni][q] + bv,
                                                &out[(size_t)gr * DD + gcol]);
            }
        }
    }
}

extern "C" void kernel_launch(void* const* d_in, const int* in_sizes, int n_in,
                              void* d_out, int out_size, void* d_ws, size_t ws_size,
                              hipStream_t stream) {
    const float* x  = (const float*)d_in[0];
    const int*   e0 = (const int*)d_in[1];
    const int*   e1 = (const int*)d_in[2];
    const int*   e2 = (const int*)d_in[3];
    const float* Wl = (const float*)d_in[4];
    const float* bl = (const float*)d_in[5];
    const float* Wr = (const float*)d_in[6];
    const float* P1 = (const float*)d_in[7];
    const float* b1 = (const float*)d_in[8];
    const float* P2 = (const float*)d_in[9];
    const float* b2 = (const float*)d_in[10];
    float* out = (float*)d_out;

    // ws layout (~122 MB)
    ushort* xh       = (ushort*)d_ws;                     // (N+1)*D    (25.6 MB; row N = zeros)
    ushort* aggh     = xh + (size_t)(NN + 1) * DD;        // R*N*D      (76.8 MB)
    ushort* QBt      = aggh + (size_t)RR * NN * DD;       // 128*512
    ushort* P2t      = QBt + (size_t)128 * 512;           // 128*128
    float*  cb       = (float*)(P2t + (size_t)DD * DD);   // D
    int*    g_cursor = (int*)(cb + DD);                   // NBIN
    int*    g_bindat = g_cursor + NBIN;                   // NBIN*BCAP_RAW (7.2 MB)
    int*    sorted   = g_bindat + (size_t)NBIN * BCAP_RAW;// NBIN*BCAP_PAD + 64 slack (9.6 MB)
    uint2*  meta     = (uint2*)(sorted + (size_t)NBIN * BCAP_PAD + 64);  // MM uint2

    (void)hipMemsetAsync(g_cursor, 0, NBIN * sizeof(int), stream);

    prep_kernel<<<ABLOCKS + TBLOCKS + PBLOCKS, 256, 0, stream>>>(
        e0, e1, e2, g_cursor, g_bindat, x, xh,
        Wl, Wr, P1, b1, bl, P2, QBt, P2t, cb);

    sort_kernel<<<NBIN, 256, 0, stream>>>(g_cursor, g_bindat, sorted, meta);

    aggregate_kernel<<<MM / 32, 256, 0, stream>>>(xh, sorted, meta, aggh);

    int gblocks = (NN + 127) / 128;
    gemm_fused_kernel<<<gblocks, 256, 0, stream>>>(xh, aggh, QBt, cb, P2t, b2, out);
}

// Round 18
// 181.683 us; speedup vs baseline: 1.0838x; 1.0380x over previous
//
#include <hip/hip_runtime.h>
#include <hip/hip_bf16.h>

#define NN 100000
#define DD 128
#define EE 500000
#define RR 3
#define MM (RR * NN)          // total buckets = 300000
#define NBIN 293              // ceil(MM / 1024) coarse bins
#define BCAP_RAW 6144         // per-bin raw capacity (Poisson mean 5120, +14 sigma)
#define BCAP_PAD 8192         // per-bin padded capacity (pad4: mean ~6700, ~18 sigma)

#define ABLOCKS 367           // (RR*EE + 4095)/4096  : bin chunks
#define TBLOCKS 12501         // ceil((NN+1)*DD/4 / 256) : tobf16 blocks
#define PBLOCKS 321           // ceil(641/2)           : precompute pairs

typedef __attribute__((ext_vector_type(8))) short   bf16x8;
typedef __attribute__((ext_vector_type(8))) ushort  ushort8;
typedef __attribute__((ext_vector_type(4))) float   f32x4;
typedef __attribute__((ext_vector_type(2))) unsigned uintx2;   // nt-load-compatible uint2

__device__ __forceinline__ ushort f2bf(float f) {
    __hip_bfloat16 h = __float2bfloat16(f);   // RNE
    return *(ushort*)&h;
}
__device__ __forceinline__ float bflo(unsigned v) {
    unsigned u = v << 16;
    return *(float*)&u;
}
__device__ __forceinline__ float bfhi(unsigned v) {
    unsigned u = v & 0xffff0000u;
    return *(float*)&u;
}

// ---------------- merged front-end: bin + x->bf16 + precompute ----------------
// blocks [0, ABLOCKS)                      : coarse edge binning
// blocks [ABLOCKS, ABLOCKS+TBLOCKS)        : x -> bf16 (+ zero row NN)
// blocks [ABLOCKS+TBLOCKS, +PBLOCKS)       : QBt / P2t / cb precompute (2 orig per block)
// All three regions are read/write-disjoint; g_cursor is pre-zeroed via memsetAsync.
__global__ __launch_bounds__(256) void prep_kernel(
    const int* __restrict__ e0, const int* __restrict__ e1, const int* __restrict__ e2,
    int* __restrict__ g_cursor, int* __restrict__ g_bindata,
    const float* __restrict__ x, ushort* __restrict__ xh,
    const float* __restrict__ Wl, const float* __restrict__ Wr,
    const float* __restrict__ P1, const float* __restrict__ b1,
    const float* __restrict__ bl, const float* __restrict__ P2,
    ushort* __restrict__ QBt, ushort* __restrict__ P2t, float* __restrict__ cb)
{
    __shared__ int hist[NBIN];
    __shared__ int base[NBIN];
    int blk = blockIdx.x;
    int tid = threadIdx.x;

    if (blk < ABLOCKS) {
        // ---- coarse binning: packed word = src | (local << 17) ----
        for (int i = tid; i < NBIN; i += 256) hist[i] = 0;
        __syncthreads();
        int e_begin = blk * 4096;
        int e_end = e_begin + 4096; if (e_end > RR * EE) e_end = RR * EE;
        for (int i = e_begin + tid; i < e_end; i += 256) {
            int r = i / EE, e = i - r * EE;
            const int* ei = (r == 0) ? e0 : (r == 1) ? e1 : e2;
            int bin = (r * NN + ei[EE + e]) >> 10;
            atomicAdd(&hist[bin], 1);
        }
        __syncthreads();
        for (int i = tid; i < NBIN; i += 256) {
            int c = hist[i];
            base[i] = c ? atomicAdd(&g_cursor[i], c) : 0;
            hist[i] = 0;
        }
        __syncthreads();
        for (int i = e_begin + tid; i < e_end; i += 256) {
            int r = i / EE, e = i - r * EE;
            const int* ei = (r == 0) ? e0 : (r == 1) ? e1 : e2;
            int src = ei[e];
            int b = r * NN + ei[EE + e];
            int bin = b >> 10, local = b & 1023;
            int slot = base[bin] + atomicAdd(&hist[bin], 1);
            if (slot < BCAP_RAW)
                g_bindata[(size_t)bin * BCAP_RAW + slot] = src | (local << 17);
        }
    } else if (blk < ABLOCKS + TBLOCKS) {
        // ---- x -> bf16 (4 elems/thread); tail zeroes row NN ----
        size_t i = (size_t)(blk - ABLOCKS) * 256 + tid;
        if (i * 4 >= (size_t)NN * DD) {
            if (i * 4 < (size_t)(NN + 1) * DD)
                ((uint2*)xh)[i] = make_uint2(0u, 0u);
            return;
        }
        float4 v = ((const float4*)x)[i];
        unsigned lo = (unsigned)f2bf(v.x) | ((unsigned)f2bf(v.y) << 16);
        unsigned hi = (unsigned)f2bf(v.z) | ((unsigned)f2bf(v.w) << 16);
        ((uint2*)xh)[i] = make_uint2(lo, hi);
    } else {
        // ---- precompute: 2 original 128-thread blocks per physical block ----
        int orig = (blk - ABLOCKS - TBLOCKS) * 2 + (tid >> 7);
        int j = tid & 127;
        if (orig >= 641) return;
        if (orig < 4 * DD) {
            int s = orig >> 7;   // 0..3
            int i = orig & 127;  // k within segment
            float acc = 0.f;
            if (s == 0) {
                for (int r = 0; r < RR; ++r) {
                    const float* wrow = Wr + (size_t)(r * DD + i) * DD;
                    const float* pcol = P1 + (size_t)(r * DD) * DD + j;
                    for (int k = 0; k < DD; ++k)
                        acc += wrow[k] * pcol[(size_t)k * DD];
                }
            } else {
                int r = s - 1;
                const float* wrow = Wl + (size_t)(r * DD + i) * DD;
                const float* pcol = P1 + (size_t)(r * DD) * DD + j;
                for (int k = 0; k < DD; ++k)
                    acc += wrow[k] * pcol[(size_t)k * DD];
            }
            QBt[(size_t)j * 512 + s * DD + i] = f2bf(acc);
        } else if (orig < 4 * DD + DD) {
            int jj = orig - 4 * DD;   // output col
            P2t[(size_t)jj * DD + j] = f2bf(P2[(size_t)j * DD + jj]);
        } else {
            float acc = b1[j];
            for (int r = 0; r < RR; ++r)
                for (int k = 0; k < DD; ++k)
                    acc += bl[r * DD + k] * P1[(size_t)(r * DD + k) * DD + j];
            cb[j] = acc;
        }
    }
}

// ---------------- phase B: per-bin local sort -> exact CSR, 4-padded ----------------
// bucket segments padded to multiple of 4 with src = NN (zero row of xh)
// meta[bucket] = {global start, raw deg}
__global__ __launch_bounds__(256) void sort_kernel(
    const int* __restrict__ g_cursor, const int* __restrict__ g_bindata,
    int* __restrict__ sorted, uint2* __restrict__ meta)
{
    __shared__ int hist[1024];
    __shared__ int start[1024];
    __shared__ int ssum[256];
    int bin = blockIdx.x, tid = threadIdx.x;
    int cnt = g_cursor[bin]; if (cnt > BCAP_RAW) cnt = BCAP_RAW;
    const int* bd = g_bindata + (size_t)bin * BCAP_RAW;
    for (int i = tid; i < 1024; i += 256) hist[i] = 0;
    __syncthreads();
    for (int i = tid; i < cnt; i += 256)
        atomicAdd(&hist[bd[i] >> 17], 1);
    __syncthreads();
    // exclusive scan over PADDED (mult-of-4) lengths (4 per thread + block scan)
    int t4 = tid * 4;
    int a0 = hist[t4], a1 = hist[t4 + 1], a2 = hist[t4 + 2], a3 = hist[t4 + 3];
    int p0 = (a0 + 3) & ~3, p1 = (a1 + 3) & ~3, p2 = (a2 + 3) & ~3, p3 = (a3 + 3) & ~3;
    int ts = p0 + p1 + p2 + p3;
    ssum[tid] = ts;
    __syncthreads();
    #pragma unroll
    for (int off = 1; off < 256; off <<= 1) {
        int tmp = (tid >= off) ? ssum[tid - off] : 0;
        __syncthreads();
        ssum[tid] += tmp;
        __syncthreads();
    }
    int ex = ssum[tid] - ts;
    start[t4] = ex; start[t4 + 1] = ex + p0;
    start[t4 + 2] = ex + p0 + p1; start[t4 + 3] = ex + p0 + p1 + p2;
    __syncthreads();
    // CSR meta (packed) + convert hist -> cursors
    for (int i = tid; i < 1024; i += 256) {
        int bucket = (bin << 10) + i;
        if (bucket < MM)
            meta[bucket] = make_uint2((unsigned)(bin * BCAP_PAD + start[i]),
                                      (unsigned)hist[i]);
        hist[i] = start[i];
    }
    __syncthreads();
    int* sb = sorted + (size_t)bin * BCAP_PAD;
    // scatter srcs bucket-contiguous (writes confined to L2-resident window)
    for (int i = tid; i < cnt; i += 256) {
        int w = bd[i];
        int pos = atomicAdd(&hist[w >> 17], 1);
        if (pos < BCAP_PAD) sb[pos] = w & 0x1ffff;
    }
    __syncthreads();
    // pad fill: positions [start+d, start+padlen) get zero-row index NN
    for (int i = tid; i < 1024; i += 256) {
        int s0 = start[i];
        int d = hist[i] - s0;              // final cursor - start = raw count
        int pl = (d + 3) & ~3;
        for (int p = s0 + d; p < s0 + pl; ++p)
            if (p < BCAP_PAD) sb[p] = NN;
    }
}

// ---------------- gather-aggregate: 8 buckets/wave, pad4, NT loads ----------------
// one meta round + one sidx preload covers 8 buckets (L<=64 for ~97% of groups).
// AT CEILING: logical gather 416 MB / 66 us = 6.3 TB/s = achievable HBM stream rate.
__global__ __launch_bounds__(256) void aggregate_kernel(
    const ushort* __restrict__ xh, const int* __restrict__ sorted,
    const uint2* __restrict__ meta, ushort* __restrict__ aggh)
{
    int grp = blockIdx.x * 4 + (threadIdx.x >> 6);   // group of 8 buckets; grid = MM/32
    int lane = threadIdx.x & 63;
    int bid0 = grp * 8;                              // 8 consecutive buckets, same bin
    uintx2 m = __builtin_nontemporal_load(
        (const uintx2*)meta + (bid0 + (lane & 7)));  // one load round for all 8 metas
    int st[8], dg[8];
    #pragma unroll
    for (int b = 0; b < 8; ++b) {
        st[b] = __builtin_amdgcn_readlane((int)m.x, b);
        dg[b] = __builtin_amdgcn_readlane((int)m.y, b);
    }
    int start0 = st[0];
    int L = (st[7] - start0) + ((dg[7] + 3) & ~3);   // combined padded length (mean ~52)
    const unsigned* xu = (const unsigned*)xh;
    float ax[8], ay[8];
    #pragma unroll
    for (int b = 0; b < 8; ++b) { ax[b] = 0.f; ay[b] = 0.f; }

    if (L <= 64) {                                   // ~97% of groups
        int sidx = __builtin_nontemporal_load(&sorted[start0 + lane]);
        #pragma unroll
        for (int b = 0; b < 8; ++b) {
            int off = st[b] - start0;
            int degp = (dg[b] + 3) & ~3;
            for (int j = 0; j < degp; j += 4) {
                #pragma unroll
                for (int u = 0; u < 4; ++u) {
                    int sj = __builtin_amdgcn_readlane(sidx, off + j + u); // SGPR row idx
                    unsigned v = xu[(size_t)sj * 64 + lane];               // SGPR-base gather
                    ax[b] += bflo(v);
                    ay[b] += bfhi(v);
                }
            }
        }
    } else {                                         // fallback: uniform-addr loads
        #pragma unroll
        for (int b = 0; b < 8; ++b) {
            const int* sb = sorted + st[b];
            int degp = (dg[b] + 3) & ~3;
            for (int j = 0; j < degp; j += 4) {
                #pragma unroll
                for (int u = 0; u < 4; ++u) {
                    int sj = sb[j + u];              // padded: always valid
                    unsigned v = xu[(size_t)sj * 64 + lane];
                    ax[b] += bflo(v);
                    ay[b] += bfhi(v);
                }
            }
        }
    }
    #pragma unroll
    for (int b = 0; b < 8; ++b) {
        int deg = dg[b];
        float sc = 1.0f / (float)(deg > 1 ? deg : 1);
        unsigned o = (unsigned)f2bf(ax[b] * sc) | ((unsigned)f2bf(ay[b] * sc) << 16);
        ((unsigned*)(aggh + (size_t)(bid0 + b) * DD))[lane] = o;   // plain store: L3-warm
    }
}

// ---------------- fused GEMM: out = relu([xh|agg]@QBt^T + cb) @ P2t^T + b2 ----------
// Stage1: 128x128 h-tile via 8 K-chunks; A-tile SOFTWARE-PIPELINED (prefetch chunk c+1
// into regs while chunk c's MFMA runs); B staged in LDS (L2-hot QBt, short latency).
// Stage2: P2t B-fragments in REGISTERS; Hs overlays As/Bs. LDS = 36,864 B.
__global__ __launch_bounds__(256) void gemm_fused_kernel(
    const ushort* __restrict__ xh, const ushort* __restrict__ aggh,
    const ushort* __restrict__ QBt, const float* __restrict__ cb,
    const ushort* __restrict__ P2t, const float* __restrict__ b2,
    float* __restrict__ out)
{
    __shared__ ushort S[18432];                        // 36,864 B
    ushort (*As)[72]  = (ushort(*)[72])S;              // stage1 A  [128][72]
    ushort (*Bs)[72]  = (ushort(*)[72])(S + 9216);     // stage1 B  [128][72]
    ushort (*Hs)[136] = (ushort(*)[136])S;             // stage2 A  [128][136] (overlays)

    int tid = threadIdx.x;
    int n0 = blockIdx.x * 128;
    int wid = tid >> 6;
    int lane = tid & 63;
    int wr = wid >> 1, wc = wid & 1;
    int lrow = lane & 15;
    int lk = (lane >> 4) * 8;

    f32x4 acc[4][4];
    #pragma unroll
    for (int i = 0; i < 4; ++i)
        #pragma unroll
        for (int j = 0; j < 4; ++j) acc[i][j] = (f32x4){0.f, 0.f, 0.f, 0.f};

    // A-tile register prefetch buffer: 4 x 16B per thread
    ushort8 ra[4];
    auto loadA = [&](int c, ushort8* v) {
        int seg = c >> 1, kloc = (c & 1) * 64;
        const ushort* Abase = (seg == 0) ? xh : (aggh + (size_t)(seg - 1) * NN * DD);
        #pragma unroll
        for (int i = 0; i < 4; ++i) {
            int id = tid + i * 256;
            int row = id >> 3, s16 = id & 7;
            int grow = n0 + row;
            ushort8 t = {0, 0, 0, 0, 0, 0, 0, 0};
            if (grow < NN)
                t = *(const ushort8*)(Abase + (size_t)grow * DD + kloc + s16 * 8);
            v[i] = t;
        }
    };

    loadA(0, ra);

    for (int c = 0; c < 8; ++c) {
        if (c) __syncthreads();                // prev MFMA done reading As/Bs
        // write prefetched A-tile (chunk c) into LDS
        #pragma unroll
        for (int i = 0; i < 4; ++i) {
            int id = tid + i * 256;
            int row = id >> 3, s16 = id & 7;
            *(ushort8*)&As[row][s16 * 8] = ra[i];
        }
        // stage B (L2-hot QBt) into LDS
        #pragma unroll
        for (int i = 0; i < 4; ++i) {
            int id = tid + i * 256;
            int n = id >> 3, s16 = id & 7;
            *(ushort8*)&Bs[n][s16 * 8] =
                *(const ushort8*)(QBt + (size_t)n * 512 + c * 64 + s16 * 8);
        }
        if (c < 7) loadA(c + 1, ra);           // issue early: flies during barrier+MFMA
        __syncthreads();
        #pragma unroll
        for (int ks = 0; ks < 2; ++ks) {
            bf16x8 a[4], b[4];
            #pragma unroll
            for (int mi = 0; mi < 4; ++mi)
                a[mi] = *(const bf16x8*)&As[wr * 64 + mi * 16 + lrow][ks * 32 + lk];
            #pragma unroll
            for (int ni = 0; ni < 4; ++ni)
                b[ni] = *(const bf16x8*)&Bs[wc * 64 + ni * 16 + lrow][ks * 32 + lk];
            #pragma unroll
            for (int mi = 0; mi < 4; ++mi)
                #pragma unroll
                for (int ni = 0; ni < 4; ++ni)
                    acc[mi][ni] = __builtin_amdgcn_mfma_f32_16x16x32_bf16(
                        a[mi], b[ni], acc[mi][ni], 0, 0, 0);
        }
    }

    // stage2 B-fragments from global (L2-broadcast) — issue BEFORE the barrier so
    // the ~200cy L2 latency hides under the sync + Hs writes.
    bf16x8 pb[4][4];   // [ks][ni]
    #pragma unroll
    for (int ks = 0; ks < 4; ++ks)
        #pragma unroll
        for (int ni = 0; ni < 4; ++ni)
            pb[ks][ni] = *(const bf16x8*)(P2t +
                (size_t)(wc * 64 + ni * 16 + lrow) * DD + ks * 32 + lk);

    __syncthreads();   // all stage1 LDS reads done before repurposing as Hs

    // epilogue1: h = relu(acc + cb) -> Hs (bf16); C/D layout row=(lane>>4)*4+q, col=lane&15
    int crow = lane >> 4;
    int ccol = lane & 15;
    #pragma unroll
    for (int ni = 0; ni < 4; ++ni) {
        int gcol = wc * 64 + ni * 16 + ccol;
        float cv = cb[gcol];
        #pragma unroll
        for (int mi = 0; mi < 4; ++mi) {
            #pragma unroll
            for (int q = 0; q < 4; ++q) {
                float v = acc[mi][ni][q] + cv;
                v = v > 0.f ? v : 0.f;
                Hs[wr * 64 + mi * 16 + crow * 4 + q][gcol] = f2bf(v);
            }
        }
    }
    __syncthreads();

    f32x4 acc2[4][4];
    #pragma unroll
    for (int i = 0; i < 4; ++i)
        #pragma unroll
        for (int j = 0; j < 4; ++j) acc2[i][j] = (f32x4){0.f, 0.f, 0.f, 0.f};

    #pragma unroll
    for (int ks = 0; ks < 4; ++ks) {
        bf16x8 a[4];
        #pragma unroll
        for (int mi = 0; mi < 4; ++mi)
            a[mi] = *(const bf16x8*)&Hs[wr * 64 + mi * 16 + lrow][ks * 32 + lk];
        #pragma unroll
        for (int mi = 0; mi < 4; ++mi)
            #pragma unroll
            for (int ni = 0; ni < 4; ++ni)
                acc2[mi][ni] = __builtin_amdgcn_mfma_f32_16x16x32_bf16(
                    a[mi], pb[ks][ni], acc2[mi][ni], 0, 0, 0);
    }

    #pragma unroll
    for (int ni = 0; ni < 4; ++ni) {
        int gcol = wc * 64 + ni * 16 + ccol;
        float bv = b2[gcol];
        #pragma unroll
        for (int mi = 0; mi < 4; ++mi) {
            #pragma unroll
            for (int q = 0; q < 4; ++q) {
                int gr = n0 + wr * 64 + mi * 16 + crow * 4 + q;
                if (gr < NN)
                    __builtin_nontemporal_store(acc2[mi][ni][q] + bv,
                                                &out[(size_t)gr * DD + gcol]);
            }
        }
    }
}

extern "C" void kernel_launch(void* const* d_in, const int* in_sizes, int n_in,
                              void* d_out, int out_size, void* d_ws, size_t ws_size,
                              hipStream_t stream) {
    const float* x  = (const float*)d_in[0];
    const int*   e0 = (const int*)d_in[1];
    const int*   e1 = (const int*)d_in[2];
    const int*   e2 = (const int*)d_in[3];
    const float* Wl = (const float*)d_in[4];
    const float* bl = (const float*)d_in[5];
    const float* Wr = (const float*)d_in[6];
    const float* P1 = (const float*)d_in[7];
    const float* b1 = (const float*)d_in[8];
    const float* P2 = (const float*)d_in[9];
    const float* b2 = (const float*)d_in[10];
    float* out = (float*)d_out;

    // ws layout (~122 MB)
    ushort* xh       = (ushort*)d_ws;                     // (N+1)*D    (25.6 MB; row N = zeros)
    ushort* aggh     = xh + (size_t)(NN + 1) * DD;        // R*N*D      (76.8 MB)
    ushort* QBt      = aggh + (size_t)RR * NN * DD;       // 128*512
    ushort* P2t      = QBt + (size_t)128 * 512;           // 128*128
    float*  cb       = (float*)(P2t + (size_t)DD * DD);   // D
    int*    g_cursor = (int*)(cb + DD);                   // NBIN
    int*    g_bindat = g_cursor + NBIN;                   // NBIN*BCAP_RAW (7.2 MB)
    int*    sorted   = g_bindat + (size_t)NBIN * BCAP_RAW;// NBIN*BCAP_PAD + 64 slack (9.6 MB)
    uint2*  meta     = (uint2*)(sorted + (size_t)NBIN * BCAP_PAD + 64);  // MM uint2

    (void)hipMemsetAsync(g_cursor, 0, NBIN * sizeof(int), stream);

    prep_kernel<<<ABLOCKS + TBLOCKS + PBLOCKS, 256, 0, stream>>>(
        e0, e1, e2, g_cursor, g_bindat, x, xh,
        Wl, Wr, P1, b1, bl, P2, QBt, P2t, cb);

    sort_kernel<<<NBIN, 256, 0, stream>>>(g_cursor, g_bindat, sorted, meta);

    aggregate_kernel<<<MM / 32, 256, 0, stream>>>(xh, sorted, meta, aggh);

    int gblocks = (NN + 127) / 128;
    gemm_fused_kernel<<<gblocks, 256, 0, stream>>>(xh, aggh, QBt, cb, P2t, b2, out);
}

// Round 19
// 178.076 us; speedup vs baseline: 1.1057x; 1.0203x over previous
//
#include <hip/hip_runtime.h>
#include <hip/hip_bf16.h>

#define NN 100000
#define DD 128
#define EE 500000
#define RR 3
#define MM (RR * NN)          // total buckets = 300000
#define NBIN 293              // ceil(MM / 1024) coarse bins
#define BCAP_RAW 6144         // per-bin raw capacity (Poisson mean 5120, +14 sigma)
#define BCAP_PAD 8192         // per-bin padded capacity (pad4: mean ~6700, ~18 sigma)

#define ABLOCKS 367           // (RR*EE + 4095)/4096  : bin chunks
#define TBLOCKS 12501         // ceil((NN+1)*DD/4 / 256) : tobf16 blocks
#define PBLOCKS 321           // ceil(641/2)           : precompute pairs

typedef __attribute__((ext_vector_type(8))) short   bf16x8;
typedef __attribute__((ext_vector_type(8))) ushort  ushort8;
typedef __attribute__((ext_vector_type(4))) float   f32x4;
typedef __attribute__((ext_vector_type(2))) unsigned uintx2;   // nt-load-compatible uint2

__device__ __forceinline__ ushort f2bf(float f) {
    __hip_bfloat16 h = __float2bfloat16(f);   // RNE
    return *(ushort*)&h;
}
__device__ __forceinline__ float bflo(unsigned v) {
    unsigned u = v << 16;
    return *(float*)&u;
}
__device__ __forceinline__ float bfhi(unsigned v) {
    unsigned u = v & 0xffff0000u;
    return *(float*)&u;
}

// ---------------- merged front-end: bin + x->bf16 + precompute ----------------
__global__ __launch_bounds__(256) void prep_kernel(
    const int* __restrict__ e0, const int* __restrict__ e1, const int* __restrict__ e2,
    int* __restrict__ g_cursor, int* __restrict__ g_bindata,
    const float* __restrict__ x, ushort* __restrict__ xh,
    const float* __restrict__ Wl, const float* __restrict__ Wr,
    const float* __restrict__ P1, const float* __restrict__ b1,
    const float* __restrict__ bl, const float* __restrict__ P2,
    ushort* __restrict__ QBt, ushort* __restrict__ P2t, float* __restrict__ cb)
{
    __shared__ int hist[NBIN];
    __shared__ int base[NBIN];
    int blk = blockIdx.x;
    int tid = threadIdx.x;

    if (blk < ABLOCKS) {
        // ---- coarse binning: packed word = src | (local << 17) ----
        for (int i = tid; i < NBIN; i += 256) hist[i] = 0;
        __syncthreads();
        int e_begin = blk * 4096;
        int e_end = e_begin + 4096; if (e_end > RR * EE) e_end = RR * EE;
        for (int i = e_begin + tid; i < e_end; i += 256) {
            int r = i / EE, e = i - r * EE;
            const int* ei = (r == 0) ? e0 : (r == 1) ? e1 : e2;
            int bin = (r * NN + ei[EE + e]) >> 10;
            atomicAdd(&hist[bin], 1);
        }
        __syncthreads();
        for (int i = tid; i < NBIN; i += 256) {
            int c = hist[i];
            base[i] = c ? atomicAdd(&g_cursor[i], c) : 0;
            hist[i] = 0;
        }
        __syncthreads();
        for (int i = e_begin + tid; i < e_end; i += 256) {
            int r = i / EE, e = i - r * EE;
            const int* ei = (r == 0) ? e0 : (r == 1) ? e1 : e2;
            int src = ei[e];
            int b = r * NN + ei[EE + e];
            int bin = b >> 10, local = b & 1023;
            int slot = base[bin] + atomicAdd(&hist[bin], 1);
            if (slot < BCAP_RAW)
                g_bindata[(size_t)bin * BCAP_RAW + slot] = src | (local << 17);
        }
    } else if (blk < ABLOCKS + TBLOCKS) {
        // ---- x -> bf16 (4 elems/thread); tail zeroes row NN ----
        size_t i = (size_t)(blk - ABLOCKS) * 256 + tid;
        if (i * 4 >= (size_t)NN * DD) {
            if (i * 4 < (size_t)(NN + 1) * DD)
                ((uint2*)xh)[i] = make_uint2(0u, 0u);
            return;
        }
        float4 v = ((const float4*)x)[i];
        unsigned lo = (unsigned)f2bf(v.x) | ((unsigned)f2bf(v.y) << 16);
        unsigned hi = (unsigned)f2bf(v.z) | ((unsigned)f2bf(v.w) << 16);
        ((uint2*)xh)[i] = make_uint2(lo, hi);
    } else {
        // ---- precompute: 2 original 128-thread blocks per physical block ----
        int orig = (blk - ABLOCKS - TBLOCKS) * 2 + (tid >> 7);
        int j = tid & 127;
        if (orig >= 641) return;
        if (orig < 4 * DD) {
            int s = orig >> 7;   // 0..3
            int i = orig & 127;  // k within segment
            float acc = 0.f;
            if (s == 0) {
                for (int r = 0; r < RR; ++r) {
                    const float* wrow = Wr + (size_t)(r * DD + i) * DD;
                    const float* pcol = P1 + (size_t)(r * DD) * DD + j;
                    for (int k = 0; k < DD; ++k)
                        acc += wrow[k] * pcol[(size_t)k * DD];
                }
            } else {
                int r = s - 1;
                const float* wrow = Wl + (size_t)(r * DD + i) * DD;
                const float* pcol = P1 + (size_t)(r * DD) * DD + j;
                for (int k = 0; k < DD; ++k)
                    acc += wrow[k] * pcol[(size_t)k * DD];
            }
            QBt[(size_t)j * 512 + s * DD + i] = f2bf(acc);
        } else if (orig < 4 * DD + DD) {
            int jj = orig - 4 * DD;   // output col
            P2t[(size_t)jj * DD + j] = f2bf(P2[(size_t)j * DD + jj]);
        } else {
            float acc = b1[j];
            for (int r = 0; r < RR; ++r)
                for (int k = 0; k < DD; ++k)
                    acc += bl[r * DD + k] * P1[(size_t)(r * DD + k) * DD + j];
            cb[j] = acc;
        }
    }
}

// ---------------- phase B: per-bin local sort -> exact CSR, 4-padded ----------------
__global__ __launch_bounds__(256) void sort_kernel(
    const int* __restrict__ g_cursor, const int* __restrict__ g_bindata,
    int* __restrict__ sorted, uint2* __restrict__ meta)
{
    __shared__ int hist[1024];
    __shared__ int start[1024];
    __shared__ int ssum[256];
    int bin = blockIdx.x, tid = threadIdx.x;
    int cnt = g_cursor[bin]; if (cnt > BCAP_RAW) cnt = BCAP_RAW;
    const int* bd = g_bindata + (size_t)bin * BCAP_RAW;
    for (int i = tid; i < 1024; i += 256) hist[i] = 0;
    __syncthreads();
    for (int i = tid; i < cnt; i += 256)
        atomicAdd(&hist[bd[i] >> 17], 1);
    __syncthreads();
    // exclusive scan over PADDED (mult-of-4) lengths (4 per thread + block scan)
    int t4 = tid * 4;
    int a0 = hist[t4], a1 = hist[t4 + 1], a2 = hist[t4 + 2], a3 = hist[t4 + 3];
    int p0 = (a0 + 3) & ~3, p1 = (a1 + 3) & ~3, p2 = (a2 + 3) & ~3, p3 = (a3 + 3) & ~3;
    int ts = p0 + p1 + p2 + p3;
    ssum[tid] = ts;
    __syncthreads();
    #pragma unroll
    for (int off = 1; off < 256; off <<= 1) {
        int tmp = (tid >= off) ? ssum[tid - off] : 0;
        __syncthreads();
        ssum[tid] += tmp;
        __syncthreads();
    }
    int ex = ssum[tid] - ts;
    start[t4] = ex; start[t4 + 1] = ex + p0;
    start[t4 + 2] = ex + p0 + p1; start[t4 + 3] = ex + p0 + p1 + p2;
    __syncthreads();
    // CSR meta (packed) + convert hist -> cursors
    for (int i = tid; i < 1024; i += 256) {
        int bucket = (bin << 10) + i;
        if (bucket < MM)
            meta[bucket] = make_uint2((unsigned)(bin * BCAP_PAD + start[i]),
                                      (unsigned)hist[i]);
        hist[i] = start[i];
    }
    __syncthreads();
    int* sb = sorted + (size_t)bin * BCAP_PAD;
    // scatter srcs bucket-contiguous (writes confined to L2-resident window)
    for (int i = tid; i < cnt; i += 256) {
        int w = bd[i];
        int pos = atomicAdd(&hist[w >> 17], 1);
        if (pos < BCAP_PAD) sb[pos] = w & 0x1ffff;
    }
    __syncthreads();
    // pad fill: positions [start+d, start+padlen) get zero-row index NN
    for (int i = tid; i < 1024; i += 256) {
        int s0 = start[i];
        int d = hist[i] - s0;              // final cursor - start = raw count
        int pl = (d + 3) & ~3;
        for (int p = s0 + d; p < s0 + pl; ++p)
            if (p < BCAP_PAD) sb[p] = NN;
    }
}

// ---------------- gather-aggregate: 8 buckets/wave, pad4, NT loads ----------------
// AT CEILING: logical gather ~416 MB / 65 us = 6.3 TB/s = achievable HBM stream rate.
__global__ __launch_bounds__(256) void aggregate_kernel(
    const ushort* __restrict__ xh, const int* __restrict__ sorted,
    const uint2* __restrict__ meta, ushort* __restrict__ aggh)
{
    int grp = blockIdx.x * 4 + (threadIdx.x >> 6);   // group of 8 buckets; grid = MM/32
    int lane = threadIdx.x & 63;
    int bid0 = grp * 8;                              // 8 consecutive buckets, same bin
    uintx2 m = __builtin_nontemporal_load(
        (const uintx2*)meta + (bid0 + (lane & 7)));  // one load round for all 8 metas
    int st[8], dg[8];
    #pragma unroll
    for (int b = 0; b < 8; ++b) {
        st[b] = __builtin_amdgcn_readlane((int)m.x, b);
        dg[b] = __builtin_amdgcn_readlane((int)m.y, b);
    }
    int start0 = st[0];
    int L = (st[7] - start0) + ((dg[7] + 3) & ~3);   // combined padded length (mean ~52)
    const unsigned* xu = (const unsigned*)xh;
    float ax[8], ay[8];
    #pragma unroll
    for (int b = 0; b < 8; ++b) { ax[b] = 0.f; ay[b] = 0.f; }

    if (L <= 64) {                                   // ~97% of groups
        int sidx = __builtin_nontemporal_load(&sorted[start0 + lane]);
        #pragma unroll
        for (int b = 0; b < 8; ++b) {
            int off = st[b] - start0;
            int degp = (dg[b] + 3) & ~3;
            for (int j = 0; j < degp; j += 4) {
                #pragma unroll
                for (int u = 0; u < 4; ++u) {
                    int sj = __builtin_amdgcn_readlane(sidx, off + j + u); // SGPR row idx
                    unsigned v = xu[(size_t)sj * 64 + lane];               // SGPR-base gather
                    ax[b] += bflo(v);
                    ay[b] += bfhi(v);
                }
            }
        }
    } else {                                         // fallback: uniform-addr loads
        #pragma unroll
        for (int b = 0; b < 8; ++b) {
            const int* sb = sorted + st[b];
            int degp = (dg[b] + 3) & ~3;
            for (int j = 0; j < degp; j += 4) {
                #pragma unroll
                for (int u = 0; u < 4; ++u) {
                    int sj = sb[j + u];              // padded: always valid
                    unsigned v = xu[(size_t)sj * 64 + lane];
                    ax[b] += bflo(v);
                    ay[b] += bfhi(v);
                }
            }
        }
    }
    #pragma unroll
    for (int b = 0; b < 8; ++b) {
        int deg = dg[b];
        float sc = 1.0f / (float)(deg > 1 ? deg : 1);
        unsigned o = (unsigned)f2bf(ax[b] * sc) | ((unsigned)f2bf(ay[b] * sc) << 16);
        ((unsigned*)(aggh + (size_t)(bid0 + b) * DD))[lane] = o;   // plain store: L3-warm
    }
}

// ---------------- fused GEMM: out = relu([xh|agg]@QBt^T + cb) @ P2t^T + b2 ----------
// Stage1: 128x128 h-tile via 8 K-chunks; BOTH A and B software-pipelined (prefetch
// chunk c+1 into regs while chunk c's MFMA runs; only ds_write->barrier->ds_read on
// the per-chunk critical path). Stage2: P2t frags in regs; Hs overlays. LDS 36,864 B.
__global__ __launch_bounds__(256) void gemm_fused_kernel(
    const ushort* __restrict__ xh, const ushort* __restrict__ aggh,
    const ushort* __restrict__ QBt, const float* __restrict__ cb,
    const ushort* __restrict__ P2t, const float* __restrict__ b2,
    float* __restrict__ out)
{
    __shared__ ushort S[18432];                        // 36,864 B
    ushort (*As)[72]  = (ushort(*)[72])S;              // stage1 A  [128][72]
    ushort (*Bs)[72]  = (ushort(*)[72])(S + 9216);     // stage1 B  [128][72]
    ushort (*Hs)[136] = (ushort(*)[136])S;             // stage2 A  [128][136] (overlays)

    int tid = threadIdx.x;
    int n0 = blockIdx.x * 128;
    int wid = tid >> 6;
    int lane = tid & 63;
    int wr = wid >> 1, wc = wid & 1;
    int lrow = lane & 15;
    int lk = (lane >> 4) * 8;

    f32x4 acc[4][4];
    #pragma unroll
    for (int i = 0; i < 4; ++i)
        #pragma unroll
        for (int j = 0; j < 4; ++j) acc[i][j] = (f32x4){0.f, 0.f, 0.f, 0.f};

    // register prefetch buffers: 4 x 16B each for A and B
    ushort8 ra[4], rb[4];
    auto loadA = [&](int c, ushort8* v) {
        int seg = c >> 1, kloc = (c & 1) * 64;
        const ushort* Abase = (seg == 0) ? xh : (aggh + (size_t)(seg - 1) * NN * DD);
        #pragma unroll
        for (int i = 0; i < 4; ++i) {
            int id = tid + i * 256;
            int row = id >> 3, s16 = id & 7;
            int grow = n0 + row;
            ushort8 t = {0, 0, 0, 0, 0, 0, 0, 0};
            if (grow < NN)
                t = *(const ushort8*)(Abase + (size_t)grow * DD + kloc + s16 * 8);
            v[i] = t;
        }
    };
    auto loadB = [&](int c, ushort8* v) {
        #pragma unroll
        for (int i = 0; i < 4; ++i) {
            int id = tid + i * 256;
            int n = id >> 3, s16 = id & 7;
            v[i] = *(const ushort8*)(QBt + (size_t)n * 512 + c * 64 + s16 * 8);
        }
    };

    loadA(0, ra);
    loadB(0, rb);

    for (int c = 0; c < 8; ++c) {
        if (c) __syncthreads();                // prev MFMA done reading As/Bs
        // write prefetched tiles (chunk c) into LDS
        #pragma unroll
        for (int i = 0; i < 4; ++i) {
            int id = tid + i * 256;
            int row = id >> 3, s16 = id & 7;
            *(ushort8*)&As[row][s16 * 8] = ra[i];
            *(ushort8*)&Bs[row][s16 * 8] = rb[i];
        }
        if (c < 7) { loadA(c + 1, ra); loadB(c + 1, rb); }  // fly during barrier+MFMA
        __syncthreads();
        #pragma unroll
        for (int ks = 0; ks < 2; ++ks) {
            bf16x8 a[4], b[4];
            #pragma unroll
            for (int mi = 0; mi < 4; ++mi)
                a[mi] = *(const bf16x8*)&As[wr * 64 + mi * 16 + lrow][ks * 32 + lk];
            #pragma unroll
            for (int ni = 0; ni < 4; ++ni)
                b[ni] = *(const bf16x8*)&Bs[wc * 64 + ni * 16 + lrow][ks * 32 + lk];
            #pragma unroll
            for (int mi = 0; mi < 4; ++mi)
                #pragma unroll
                for (int ni = 0; ni < 4; ++ni)
                    acc[mi][ni] = __builtin_amdgcn_mfma_f32_16x16x32_bf16(
                        a[mi], b[ni], acc[mi][ni], 0, 0, 0);
        }
    }

    // stage2 B-fragments from global (L2-broadcast) — issue before the barrier
    bf16x8 pb[4][4];   // [ks][ni]
    #pragma unroll
    for (int ks = 0; ks < 4; ++ks)
        #pragma unroll
        for (int ni = 0; ni < 4; ++ni)
            pb[ks][ni] = *(const bf16x8*)(P2t +
                (size_t)(wc * 64 + ni * 16 + lrow) * DD + ks * 32 + lk);

    __syncthreads();   // all stage1 LDS reads done before repurposing as Hs

    // epilogue1: h = relu(acc + cb) -> Hs (bf16); C/D layout row=(lane>>4)*4+q, col=lane&15
    int crow = lane >> 4;
    int ccol = lane & 15;
    #pragma unroll
    for (int ni = 0; ni < 4; ++ni) {
        int gcol = wc * 64 + ni * 16 + ccol;
        float cv = cb[gcol];
        #pragma unroll
        for (int mi = 0; mi < 4; ++mi) {
            #pragma unroll
            for (int q = 0; q < 4; ++q) {
                float v = acc[mi][ni][q] + cv;
                v = v > 0.f ? v : 0.f;
                Hs[wr * 64 + mi * 16 + crow * 4 + q][gcol] = f2bf(v);
            }
        }
    }
    __syncthreads();

    f32x4 acc2[4][4];
    #pragma unroll
    for (int i = 0; i < 4; ++i)
        #pragma unroll
        for (int j = 0; j < 4; ++j) acc2[i][j] = (f32x4){0.f, 0.f, 0.f, 0.f};

    #pragma unroll
    for (int ks = 0; ks < 4; ++ks) {
        bf16x8 a[4];
        #pragma unroll
        for (int mi = 0; mi < 4; ++mi)
            a[mi] = *(const bf16x8*)&Hs[wr * 64 + mi * 16 + lrow][ks * 32 + lk];
        #pragma unroll
        for (int mi = 0; mi < 4; ++mi)
            #pragma unroll
            for (int ni = 0; ni < 4; ++ni)
                acc2[mi][ni] = __builtin_amdgcn_mfma_f32_16x16x32_bf16(
                    a[mi], pb[ks][ni], acc2[mi][ni], 0, 0, 0);
    }

    #pragma unroll
    for (int ni = 0; ni < 4; ++ni) {
        int gcol = wc * 64 + ni * 16 + ccol;
        float bv = b2[gcol];
        #pragma unroll
        for (int mi = 0; mi < 4; ++mi) {
            #pragma unroll
            for (int q = 0; q < 4; ++q) {
                int gr = n0 + wr * 64 + mi * 16 + crow * 4 + q;
                if (gr < NN)
                    __builtin_nontemporal_store(acc2[mi][ni][q] + bv,
                                                &out[(size_t)gr * DD + gcol]);
            }
        }
    }
}

extern "C" void kernel_launch(void* const* d_in, const int* in_sizes, int n_in,
                              void* d_out, int out_size, void* d_ws, size_t ws_size,
                              hipStream_t stream) {
    const float* x  = (const float*)d_in[0];
    const int*   e0 = (const int*)d_in[1];
    const int*   e1 = (const int*)d_in[2];
    const int*   e2 = (const int*)d_in[3];
    const float* Wl = (const float*)d_in[4];
    const float* bl = (const float*)d_in[5];
    const float* Wr = (const float*)d_in[6];
    const float* P1 = (const float*)d_in[7];
    const float* b1 = (const float*)d_in[8];
    const float* P2 = (const float*)d_in[9];
    const float* b2 = (const float*)d_in[10];
    float* out = (float*)d_out;

    // ws layout (~122 MB)
    ushort* xh       = (ushort*)d_ws;                     // (N+1)*D    (25.6 MB; row N = zeros)
    ushort* aggh     = xh + (size_t)(NN + 1) * DD;        // R*N*D      (76.8 MB)
    ushort* QBt      = aggh + (size_t)RR * NN * DD;       // 128*512
    ushort* P2t      = QBt + (size_t)128 * 512;           // 128*128
    float*  cb       = (float*)(P2t + (size_t)DD * DD);   // D
    int*    g_cursor = (int*)(cb + DD);                   // NBIN
    int*    g_bindat = g_cursor + NBIN;                   // NBIN*BCAP_RAW (7.2 MB)
    int*    sorted   = g_bindat + (size_t)NBIN * BCAP_RAW;// NBIN*BCAP_PAD + 64 slack (9.6 MB)
    uint2*  meta     = (uint2*)(sorted + (size_t)NBIN * BCAP_PAD + 64);  // MM uint2

    (void)hipMemsetAsync(g_cursor, 0, NBIN * sizeof(int), stream);

    prep_kernel<<<ABLOCKS + TBLOCKS + PBLOCKS, 256, 0, stream>>>(
        e0, e1, e2, g_cursor, g_bindat, x, xh,
        Wl, Wr, P1, b1, bl, P2, QBt, P2t, cb);

    sort_kernel<<<NBIN, 256, 0, stream>>>(g_cursor, g_bindat, sorted, meta);

    aggregate_kernel<<<MM / 32, 256, 0, stream>>>(xh, sorted, meta, aggh);

    int gblocks = (NN + 127) / 128;
    gemm_fused_kernel<<<gblocks, 256, 0, stream>>>(xh, aggh, QBt, cb, P2t, b2, out);
}

// Round 20
// 175.608 us; speedup vs baseline: 1.1213x; 1.0141x over previous
//
#include <hip/hip_runtime.h>
#include <hip/hip_bf16.h>

#define NN 100000
#define DD 128
#define EE 500000
#define RR 3
#define MM (RR * NN)          // total buckets = 300000
#define NBIN 293              // ceil(MM / 1024) coarse bins
#define BCAP_RAW 6144         // per-bin raw capacity (Poisson mean 5120, +14 sigma)
#define BCAP_PAD 8192         // per-bin padded capacity (pad4: mean ~6700, ~18 sigma)

#define ABLOCKS 367           // (RR*EE + 4095)/4096  : bin chunks
#define TBLOCKS 12501         // ceil((NN+1)*DD/4 / 256) : tobf16 blocks
#define PBLOCKS 321           // ceil(641/2)           : precompute pairs

typedef __attribute__((ext_vector_type(8))) short   bf16x8;
typedef __attribute__((ext_vector_type(8))) ushort  ushort8;
typedef __attribute__((ext_vector_type(4))) float   f32x4;
typedef __attribute__((ext_vector_type(2))) unsigned uintx2;   // nt-load-compatible uint2

__device__ __forceinline__ ushort f2bf(float f) {
    __hip_bfloat16 h = __float2bfloat16(f);   // RNE
    return *(ushort*)&h;
}
__device__ __forceinline__ float bflo(unsigned v) {
    unsigned u = v << 16;
    return *(float*)&u;
}
__device__ __forceinline__ float bfhi(unsigned v) {
    unsigned u = v & 0xffff0000u;
    return *(float*)&u;
}

// ---------------- merged front-end: bin + x->bf16 + precompute ----------------
__global__ __launch_bounds__(256) void prep_kernel(
    const int* __restrict__ e0, const int* __restrict__ e1, const int* __restrict__ e2,
    int* __restrict__ g_cursor, int* __restrict__ g_bindata,
    const float* __restrict__ x, ushort* __restrict__ xh,
    const float* __restrict__ Wl, const float* __restrict__ Wr,
    const float* __restrict__ P1, const float* __restrict__ b1,
    const float* __restrict__ bl, const float* __restrict__ P2,
    ushort* __restrict__ QBt, ushort* __restrict__ P2t, float* __restrict__ cb)
{
    __shared__ int hist[NBIN];
    __shared__ int base[NBIN];
    int blk = blockIdx.x;
    int tid = threadIdx.x;

    if (blk < ABLOCKS) {
        // ---- coarse binning: packed word = src | (local << 17) ----
        for (int i = tid; i < NBIN; i += 256) hist[i] = 0;
        __syncthreads();
        int e_begin = blk * 4096;
        int e_end = e_begin + 4096; if (e_end > RR * EE) e_end = RR * EE;
        for (int i = e_begin + tid; i < e_end; i += 256) {
            int r = i / EE, e = i - r * EE;
            const int* ei = (r == 0) ? e0 : (r == 1) ? e1 : e2;
            int bin = (r * NN + ei[EE + e]) >> 10;
            atomicAdd(&hist[bin], 1);
        }
        __syncthreads();
        for (int i = tid; i < NBIN; i += 256) {
            int c = hist[i];
            base[i] = c ? atomicAdd(&g_cursor[i], c) : 0;
            hist[i] = 0;
        }
        __syncthreads();
        for (int i = e_begin + tid; i < e_end; i += 256) {
            int r = i / EE, e = i - r * EE;
            const int* ei = (r == 0) ? e0 : (r == 1) ? e1 : e2;
            int src = ei[e];
            int b = r * NN + ei[EE + e];
            int bin = b >> 10, local = b & 1023;
            int slot = base[bin] + atomicAdd(&hist[bin], 1);
            if (slot < BCAP_RAW)
                g_bindata[(size_t)bin * BCAP_RAW + slot] = src | (local << 17);
        }
    } else if (blk < ABLOCKS + TBLOCKS) {
        // ---- x -> bf16 (4 elems/thread); tail zeroes row NN ----
        size_t i = (size_t)(blk - ABLOCKS) * 256 + tid;
        if (i * 4 >= (size_t)NN * DD) {
            if (i * 4 < (size_t)(NN + 1) * DD)
                ((uint2*)xh)[i] = make_uint2(0u, 0u);
            return;
        }
        float4 v = ((const float4*)x)[i];
        unsigned lo = (unsigned)f2bf(v.x) | ((unsigned)f2bf(v.y) << 16);
        unsigned hi = (unsigned)f2bf(v.z) | ((unsigned)f2bf(v.w) << 16);
        ((uint2*)xh)[i] = make_uint2(lo, hi);
    } else {
        // ---- precompute: 2 original 128-thread blocks per physical block ----
        int orig = (blk - ABLOCKS - TBLOCKS) * 2 + (tid >> 7);
        int j = tid & 127;
        if (orig >= 641) return;
        if (orig < 4 * DD) {
            int s = orig >> 7;   // 0..3
            int i = orig & 127;  // k within segment
            float acc = 0.f;
            if (s == 0) {
                for (int r = 0; r < RR; ++r) {
                    const float* wrow = Wr + (size_t)(r * DD + i) * DD;
                    const float* pcol = P1 + (size_t)(r * DD) * DD + j;
                    for (int k = 0; k < DD; ++k)
                        acc += wrow[k] * pcol[(size_t)k * DD];
                }
            } else {
                int r = s - 1;
                const float* wrow = Wl + (size_t)(r * DD + i) * DD;
                const float* pcol = P1 + (size_t)(r * DD) * DD + j;
                for (int k = 0; k < DD; ++k)
                    acc += wrow[k] * pcol[(size_t)k * DD];
            }
            QBt[(size_t)j * 512 + s * DD + i] = f2bf(acc);
        } else if (orig < 4 * DD + DD) {
            int jj = orig - 4 * DD;   // output col
            P2t[(size_t)jj * DD + j] = f2bf(P2[(size_t)j * DD + jj]);
        } else {
            float acc = b1[j];
            for (int r = 0; r < RR; ++r)
                for (int k = 0; k < DD; ++k)
                    acc += bl[r * DD + k] * P1[(size_t)(r * DD + k) * DD + j];
            cb[j] = acc;
        }
    }
}

// ---------------- phase B: per-bin local sort -> exact CSR, 4-padded ----------------
// 512 threads/block: sort is only 293 blocks (1.14/CU) -> 8 waves/CU for latency hiding.
__global__ __launch_bounds__(512) void sort_kernel(
    const int* __restrict__ g_cursor, const int* __restrict__ g_bindata,
    int* __restrict__ sorted, uint2* __restrict__ meta)
{
    __shared__ int hist[1024];
    __shared__ int start[1024];
    __shared__ int ssum[512];
    int bin = blockIdx.x, tid = threadIdx.x;
    int cnt = g_cursor[bin]; if (cnt > BCAP_RAW) cnt = BCAP_RAW;
    const int* bd = g_bindata + (size_t)bin * BCAP_RAW;
    for (int i = tid; i < 1024; i += 512) hist[i] = 0;
    __syncthreads();
    for (int i = tid; i < cnt; i += 512)
        atomicAdd(&hist[bd[i] >> 17], 1);
    __syncthreads();
    // exclusive scan over PADDED (mult-of-4) lengths: 2 elems/thread + 512-wide scan
    int t2 = tid * 2;
    int a0 = hist[t2], a1 = hist[t2 + 1];
    int p0 = (a0 + 3) & ~3, p1 = (a1 + 3) & ~3;
    int ts = p0 + p1;
    ssum[tid] = ts;
    __syncthreads();
    #pragma unroll
    for (int off = 1; off < 512; off <<= 1) {
        int tmp = (tid >= off) ? ssum[tid - off] : 0;
        __syncthreads();
        ssum[tid] += tmp;
        __syncthreads();
    }
    int ex = ssum[tid] - ts;
    start[t2] = ex; start[t2 + 1] = ex + p0;
    __syncthreads();
    // CSR meta (packed) + convert hist -> cursors
    for (int i = tid; i < 1024; i += 512) {
        int bucket = (bin << 10) + i;
        if (bucket < MM)
            meta[bucket] = make_uint2((unsigned)(bin * BCAP_PAD + start[i]),
                                      (unsigned)hist[i]);
        hist[i] = start[i];
    }
    __syncthreads();
    int* sb = sorted + (size_t)bin * BCAP_PAD;
    // scatter srcs bucket-contiguous (writes confined to L2-resident window)
    for (int i = tid; i < cnt; i += 512) {
        int w = bd[i];
        int pos = atomicAdd(&hist[w >> 17], 1);
        if (pos < BCAP_PAD) sb[pos] = w & 0x1ffff;
    }
    __syncthreads();
    // pad fill: positions [start+d, start+padlen) get zero-row index NN
    for (int i = tid; i < 1024; i += 512) {
        int s0 = start[i];
        int d = hist[i] - s0;              // final cursor - start = raw count
        int pl = (d + 3) & ~3;
        for (int p = s0 + d; p < s0 + pl; ++p)
            if (p < BCAP_PAD) sb[p] = NN;
    }
}

// ---------------- gather-aggregate: 8 buckets/wave, pad4, NT loads ----------------
// AT CEILING: logical gather ~416 MB / 65 us = 6.4 TB/s combined cache delivery.
__global__ __launch_bounds__(256) void aggregate_kernel(
    const ushort* __restrict__ xh, const int* __restrict__ sorted,
    const uint2* __restrict__ meta, ushort* __restrict__ aggh)
{
    int grp = blockIdx.x * 4 + (threadIdx.x >> 6);   // group of 8 buckets; grid = MM/32
    int lane = threadIdx.x & 63;
    int bid0 = grp * 8;                              // 8 consecutive buckets, same bin
    uintx2 m = __builtin_nontemporal_load(
        (const uintx2*)meta + (bid0 + (lane & 7)));  // one load round for all 8 metas
    int st[8], dg[8];
    #pragma unroll
    for (int b = 0; b < 8; ++b) {
        st[b] = __builtin_amdgcn_readlane((int)m.x, b);
        dg[b] = __builtin_amdgcn_readlane((int)m.y, b);
    }
    int start0 = st[0];
    int L = (st[7] - start0) + ((dg[7] + 3) & ~3);   // combined padded length (mean ~52)
    const unsigned* xu = (const unsigned*)xh;
    float ax[8], ay[8];
    #pragma unroll
    for (int b = 0; b < 8; ++b) { ax[b] = 0.f; ay[b] = 0.f; }

    if (L <= 64) {                                   // ~97% of groups
        int sidx = __builtin_nontemporal_load(&sorted[start0 + lane]);
        #pragma unroll
        for (int b = 0; b < 8; ++b) {
            int off = st[b] - start0;
            int degp = (dg[b] + 3) & ~3;
            for (int j = 0; j < degp; j += 4) {
                #pragma unroll
                for (int u = 0; u < 4; ++u) {
                    int sj = __builtin_amdgcn_readlane(sidx, off + j + u); // SGPR row idx
                    unsigned v = xu[(size_t)sj * 64 + lane];               // SGPR-base gather
                    ax[b] += bflo(v);
                    ay[b] += bfhi(v);
                }
            }
        }
    } else {                                         // fallback: uniform-addr loads
        #pragma unroll
        for (int b = 0; b < 8; ++b) {
            const int* sb = sorted + st[b];
            int degp = (dg[b] + 3) & ~3;
            for (int j = 0; j < degp; j += 4) {
                #pragma unroll
                for (int u = 0; u < 4; ++u) {
                    int sj = sb[j + u];              // padded: always valid
                    unsigned v = xu[(size_t)sj * 64 + lane];
                    ax[b] += bflo(v);
                    ay[b] += bfhi(v);
                }
            }
        }
    }
    #pragma unroll
    for (int b = 0; b < 8; ++b) {
        int deg = dg[b];
        float sc = 1.0f / (float)(deg > 1 ? deg : 1);
        unsigned o = (unsigned)f2bf(ax[b] * sc) | ((unsigned)f2bf(ay[b] * sc) << 16);
        ((unsigned*)(aggh + (size_t)(bid0 + b) * DD))[lane] = o;   // plain store: L3-warm
    }
}

// ---------------- fused GEMM: out = relu([xh|agg]@QBt^T + cb) @ P2t^T + b2 ----------
// Stage1: 128x128 h-tile via 8 K-chunks; BOTH A and B software-pipelined.
// Stage2: P2t frags in regs; Hs overlays. LDS 36,864 B.
__global__ __launch_bounds__(256) void gemm_fused_kernel(
    const ushort* __restrict__ xh, const ushort* __restrict__ aggh,
    const ushort* __restrict__ QBt, const float* __restrict__ cb,
    const ushort* __restrict__ P2t, const float* __restrict__ b2,
    float* __restrict__ out)
{
    __shared__ ushort S[18432];                        // 36,864 B
    ushort (*As)[72]  = (ushort(*)[72])S;              // stage1 A  [128][72]
    ushort (*Bs)[72]  = (ushort(*)[72])(S + 9216);     // stage1 B  [128][72]
    ushort (*Hs)[136] = (ushort(*)[136])S;             // stage2 A  [128][136] (overlays)

    int tid = threadIdx.x;
    int n0 = blockIdx.x * 128;
    int wid = tid >> 6;
    int lane = tid & 63;
    int wr = wid >> 1, wc = wid & 1;
    int lrow = lane & 15;
    int lk = (lane >> 4) * 8;

    f32x4 acc[4][4];
    #pragma unroll
    for (int i = 0; i < 4; ++i)
        #pragma unroll
        for (int j = 0; j < 4; ++j) acc[i][j] = (f32x4){0.f, 0.f, 0.f, 0.f};

    // register prefetch buffers: 4 x 16B each for A and B
    ushort8 ra[4], rb[4];
    auto loadA = [&](int c, ushort8* v) {
        int seg = c >> 1, kloc = (c & 1) * 64;
        const ushort* Abase = (seg == 0) ? xh : (aggh + (size_t)(seg - 1) * NN * DD);
        #pragma unroll
        for (int i = 0; i < 4; ++i) {
            int id = tid + i * 256;
            int row = id >> 3, s16 = id & 7;
            int grow = n0 + row;
            ushort8 t = {0, 0, 0, 0, 0, 0, 0, 0};
            if (grow < NN)
                t = *(const ushort8*)(Abase + (size_t)grow * DD + kloc + s16 * 8);
            v[i] = t;
        }
    };
    auto loadB = [&](int c, ushort8* v) {
        #pragma unroll
        for (int i = 0; i < 4; ++i) {
            int id = tid + i * 256;
            int n = id >> 3, s16 = id & 7;
            v[i] = *(const ushort8*)(QBt + (size_t)n * 512 + c * 64 + s16 * 8);
        }
    };

    loadA(0, ra);
    loadB(0, rb);

    for (int c = 0; c < 8; ++c) {
        if (c) __syncthreads();                // prev MFMA done reading As/Bs
        #pragma unroll
        for (int i = 0; i < 4; ++i) {
            int id = tid + i * 256;
            int row = id >> 3, s16 = id & 7;
            *(ushort8*)&As[row][s16 * 8] = ra[i];
            *(ushort8*)&Bs[row][s16 * 8] = rb[i];
        }
        if (c < 7) { loadA(c + 1, ra); loadB(c + 1, rb); }  // fly during barrier+MFMA
        __syncthreads();
        #pragma unroll
        for (int ks = 0; ks < 2; ++ks) {
            bf16x8 a[4], b[4];
            #pragma unroll
            for (int mi = 0; mi < 4; ++mi)
                a[mi] = *(const bf16x8*)&As[wr * 64 + mi * 16 + lrow][ks * 32 + lk];
            #pragma unroll
            for (int ni = 0; ni < 4; ++ni)
                b[ni] = *(const bf16x8*)&Bs[wc * 64 + ni * 16 + lrow][ks * 32 + lk];
            #pragma unroll
            for (int mi = 0; mi < 4; ++mi)
                #pragma unroll
                for (int ni = 0; ni < 4; ++ni)
                    acc[mi][ni] = __builtin_amdgcn_mfma_f32_16x16x32_bf16(
                        a[mi], b[ni], acc[mi][ni], 0, 0, 0);
        }
    }

    // stage2 B-fragments from global (L2-broadcast) — issue before the barrier
    bf16x8 pb[4][4];   // [ks][ni]
    #pragma unroll
    for (int ks = 0; ks < 4; ++ks)
        #pragma unroll
        for (int ni = 0; ni < 4; ++ni)
            pb[ks][ni] = *(const bf16x8*)(P2t +
                (size_t)(wc * 64 + ni * 16 + lrow) * DD + ks * 32 + lk);

    __syncthreads();   // all stage1 LDS reads done before repurposing as Hs

    // epilogue1: h = relu(acc + cb) -> Hs (bf16); C/D layout row=(lane>>4)*4+q, col=lane&15
    int crow = lane >> 4;
    int ccol = lane & 15;
    #pragma unroll
    for (int ni = 0; ni < 4; ++ni) {
        int gcol = wc * 64 + ni * 16 + ccol;
        float cv = cb[gcol];
        #pragma unroll
        for (int mi = 0; mi < 4; ++mi) {
            #pragma unroll
            for (int q = 0; q < 4; ++q) {
                float v = acc[mi][ni][q] + cv;
                v = v > 0.f ? v : 0.f;
                Hs[wr * 64 + mi * 16 + crow * 4 + q][gcol] = f2bf(v);
            }
        }
    }
    __syncthreads();

    f32x4 acc2[4][4];
    #pragma unroll
    for (int i = 0; i < 4; ++i)
        #pragma unroll
        for (int j = 0; j < 4; ++j) acc2[i][j] = (f32x4){0.f, 0.f, 0.f, 0.f};

    #pragma unroll
    for (int ks = 0; ks < 4; ++ks) {
        bf16x8 a[4];
        #pragma unroll
        for (int mi = 0; mi < 4; ++mi)
            a[mi] = *(const bf16x8*)&Hs[wr * 64 + mi * 16 + lrow][ks * 32 + lk];
        #pragma unroll
        for (int mi = 0; mi < 4; ++mi)
            #pragma unroll
            for (int ni = 0; ni < 4; ++ni)
                acc2[mi][ni] = __builtin_amdgcn_mfma_f32_16x16x32_bf16(
                    a[mi], pb[ks][ni], acc2[mi][ni], 0, 0, 0);
    }

    #pragma unroll
    for (int ni = 0; ni < 4; ++ni) {
        int gcol = wc * 64 + ni * 16 + ccol;
        float bv = b2[gcol];
        #pragma unroll
        for (int mi = 0; mi < 4; ++mi) {
            #pragma unroll
            for (int q = 0; q < 4; ++q) {
                int gr = n0 + wr * 64 + mi * 16 + crow * 4 + q;
                if (gr < NN)
                    __builtin_nontemporal_store(acc2[mi][ni][q] + bv,
                                                &out[(size_t)gr * DD + gcol]);
            }
        }
    }
}

extern "C" void kernel_launch(void* const* d_in, const int* in_sizes, int n_in,
                              void* d_out, int out_size, void* d_ws, size_t ws_size,
                              hipStream_t stream) {
    const float* x  = (const float*)d_in[0];
    const int*   e0 = (const int*)d_in[1];
    const int*   e1 = (const int*)d_in[2];
    const int*   e2 = (const int*)d_in[3];
    const float* Wl = (const float*)d_in[4];
    const float* bl = (const float*)d_in[5];
    const float* Wr = (const float*)d_in[6];
    const float* P1 = (const float*)d_in[7];
    const float* b1 = (const float*)d_in[8];
    const float* P2 = (const float*)d_in[9];
    const float* b2 = (const float*)d_in[10];
    float* out = (float*)d_out;

    // ws layout (~122 MB)
    ushort* xh       = (ushort*)d_ws;                     // (N+1)*D    (25.6 MB; row N = zeros)
    ushort* aggh     = xh + (size_t)(NN + 1) * DD;        // R*N*D      (76.8 MB)
    ushort* QBt      = aggh + (size_t)RR * NN * DD;       // 128*512
    ushort* P2t      = QBt + (size_t)128 * 512;           // 128*128
    float*  cb       = (float*)(P2t + (size_t)DD * DD);   // D
    int*    g_cursor = (int*)(cb + DD);                   // NBIN
    int*    g_bindat = g_cursor + NBIN;                   // NBIN*BCAP_RAW (7.2 MB)
    int*    sorted   = g_bindat + (size_t)NBIN * BCAP_RAW;// NBIN*BCAP_PAD + 64 slack (9.6 MB)
    uint2*  meta     = (uint2*)(sorted + (size_t)NBIN * BCAP_PAD + 64);  // MM uint2

    (void)hipMemsetAsync(g_cursor, 0, NBIN * sizeof(int), stream);

    prep_kernel<<<ABLOCKS + TBLOCKS + PBLOCKS, 256, 0, stream>>>(
        e0, e1, e2, g_cursor, g_bindat, x, xh,
        Wl, Wr, P1, b1, bl, P2, QBt, P2t, cb);

    sort_kernel<<<NBIN, 512, 0, stream>>>(g_cursor, g_bindat, sorted, meta);

    aggregate_kernel<<<MM / 32, 256, 0, stream>>>(xh, sorted, meta, aggh);

    int gblocks = (NN + 127) / 128;
    gemm_fused_kernel<<<gblocks, 256, 0, stream>>>(xh, aggh, QBt, cb, P2t, b2, out);
}

// Round 21
// 169.452 us; speedup vs baseline: 1.1620x; 1.0363x over previous
//
#include <hip/hip_runtime.h>
#include <hip/hip_bf16.h>

#define NN 100000
#define DD 128
#define EE 500000
#define RR 3
#define MM (RR * NN)          // total buckets = 300000
#define NBIN 293              // ceil(MM / 1024) coarse bins
#define BCAP_RAW 6144         // per-bin raw capacity (Poisson mean 5120, +14 sigma)
#define BCAP_PAD 8192         // per-bin padded capacity (pad4: mean ~6700, ~18 sigma)

#define ABLOCKS 367           // (RR*EE + 4095)/4096  : bin chunks
#define TBLOCKS 12501         // ceil((NN+1)*DD/4 / 256) : tobf16 blocks
#define PBLOCKS 321           // ceil(641/2)           : precompute pairs

typedef __attribute__((ext_vector_type(8))) short   bf16x8;
typedef __attribute__((ext_vector_type(8))) ushort  ushort8;
typedef __attribute__((ext_vector_type(4))) float   f32x4;
typedef __attribute__((ext_vector_type(2))) unsigned uintx2;   // nt-load-compatible uint2

__device__ __forceinline__ ushort f2bf(float f) {
    __hip_bfloat16 h = __float2bfloat16(f);   // RNE
    return *(ushort*)&h;
}
__device__ __forceinline__ float bflo(unsigned v) {
    unsigned u = v << 16;
    return *(float*)&u;
}
__device__ __forceinline__ float bfhi(unsigned v) {
    unsigned u = v & 0xffff0000u;
    return *(float*)&u;
}

// ---------------- merged front-end: bin + x->bf16 + precompute ----------------
__global__ __launch_bounds__(256) void prep_kernel(
    const int* __restrict__ e0, const int* __restrict__ e1, const int* __restrict__ e2,
    int* __restrict__ g_cursor, int* __restrict__ g_bindata,
    const float* __restrict__ x, ushort* __restrict__ xh,
    const float* __restrict__ Wl, const float* __restrict__ Wr,
    const float* __restrict__ P1, const float* __restrict__ b1,
    const float* __restrict__ bl, const float* __restrict__ P2,
    ushort* __restrict__ QBt, ushort* __restrict__ P2t, float* __restrict__ cb)
{
    __shared__ int hist[NBIN];
    __shared__ int base[NBIN];
    int blk = blockIdx.x;
    int tid = threadIdx.x;

    if (blk < ABLOCKS) {
        // ---- coarse binning: packed word = src | (local << 17) ----
        for (int i = tid; i < NBIN; i += 256) hist[i] = 0;
        __syncthreads();
        int e_begin = blk * 4096;
        int e_end = e_begin + 4096; if (e_end > RR * EE) e_end = RR * EE;
        for (int i = e_begin + tid; i < e_end; i += 256) {
            int r = i / EE, e = i - r * EE;
            const int* ei = (r == 0) ? e0 : (r == 1) ? e1 : e2;
            int bin = (r * NN + ei[EE + e]) >> 10;
            atomicAdd(&hist[bin], 1);
        }
        __syncthreads();
        for (int i = tid; i < NBIN; i += 256) {
            int c = hist[i];
            base[i] = c ? atomicAdd(&g_cursor[i], c) : 0;
            hist[i] = 0;
        }
        __syncthreads();
        for (int i = e_begin + tid; i < e_end; i += 256) {
            int r = i / EE, e = i - r * EE;
            const int* ei = (r == 0) ? e0 : (r == 1) ? e1 : e2;
            int src = ei[e];
            int b = r * NN + ei[EE + e];
            int bin = b >> 10, local = b & 1023;
            int slot = base[bin] + atomicAdd(&hist[bin], 1);
            if (slot < BCAP_RAW)
                g_bindata[(size_t)bin * BCAP_RAW + slot] = src | (local << 17);
        }
    } else if (blk < ABLOCKS + TBLOCKS) {
        // ---- x -> bf16 (4 elems/thread); tail zeroes row NN ----
        size_t i = (size_t)(blk - ABLOCKS) * 256 + tid;
        if (i * 4 >= (size_t)NN * DD) {
            if (i * 4 < (size_t)(NN + 1) * DD)
                ((uint2*)xh)[i] = make_uint2(0u, 0u);
            return;
        }
        float4 v = ((const float4*)x)[i];
        unsigned lo = (unsigned)f2bf(v.x) | ((unsigned)f2bf(v.y) << 16);
        unsigned hi = (unsigned)f2bf(v.z) | ((unsigned)f2bf(v.w) << 16);
        ((uint2*)xh)[i] = make_uint2(lo, hi);
    } else {
        // ---- precompute: 2 original 128-thread blocks per physical block ----
        int orig = (blk - ABLOCKS - TBLOCKS) * 2 + (tid >> 7);
        int j = tid & 127;
        if (orig >= 641) return;
        if (orig < 4 * DD) {
            int s = orig >> 7;   // 0..3
            int i = orig & 127;  // k within segment
            float acc = 0.f;
            if (s == 0) {
                for (int r = 0; r < RR; ++r) {
                    const float* wrow = Wr + (size_t)(r * DD + i) * DD;
                    const float* pcol = P1 + (size_t)(r * DD) * DD + j;
                    for (int k = 0; k < DD; ++k)
                        acc += wrow[k] * pcol[(size_t)k * DD];
                }
            } else {
                int r = s - 1;
                const float* wrow = Wl + (size_t)(r * DD + i) * DD;
                const float* pcol = P1 + (size_t)(r * DD) * DD + j;
                for (int k = 0; k < DD; ++k)
                    acc += wrow[k] * pcol[(size_t)k * DD];
            }
            QBt[(size_t)j * 512 + s * DD + i] = f2bf(acc);
        } else if (orig < 4 * DD + DD) {
            int jj = orig - 4 * DD;   // output col
            P2t[(size_t)jj * DD + j] = f2bf(P2[(size_t)j * DD + jj]);
        } else {
            float acc = b1[j];
            for (int r = 0; r < RR; ++r)
                for (int k = 0; k < DD; ++k)
                    acc += bl[r * DD + k] * P1[(size_t)(r * DD + k) * DD + j];
            cb[j] = acc;
        }
    }
}

// ---------------- phase B: per-bin local sort -> exact CSR, 4-padded ----------------
// 512 threads/block: sort is only 293 blocks (1.14/CU) -> 8 waves/CU for latency hiding.
__global__ __launch_bounds__(512) void sort_kernel(
    const int* __restrict__ g_cursor, const int* __restrict__ g_bindata,
    int* __restrict__ sorted, uint2* __restrict__ meta)
{
    __shared__ int hist[1024];
    __shared__ int start[1024];
    __shared__ int ssum[512];
    int bin = blockIdx.x, tid = threadIdx.x;
    int cnt = g_cursor[bin]; if (cnt > BCAP_RAW) cnt = BCAP_RAW;
    const int* bd = g_bindata + (size_t)bin * BCAP_RAW;
    for (int i = tid; i < 1024; i += 512) hist[i] = 0;
    __syncthreads();
    for (int i = tid; i < cnt; i += 512)
        atomicAdd(&hist[bd[i] >> 17], 1);
    __syncthreads();
    // exclusive scan over PADDED (mult-of-4) lengths: 2 elems/thread + 512-wide scan
    int t2 = tid * 2;
    int a0 = hist[t2], a1 = hist[t2 + 1];
    int p0 = (a0 + 3) & ~3, p1 = (a1 + 3) & ~3;
    int ts = p0 + p1;
    ssum[tid] = ts;
    __syncthreads();
    #pragma unroll
    for (int off = 1; off < 512; off <<= 1) {
        int tmp = (tid >= off) ? ssum[tid - off] : 0;
        __syncthreads();
        ssum[tid] += tmp;
        __syncthreads();
    }
    int ex = ssum[tid] - ts;
    start[t2] = ex; start[t2 + 1] = ex + p0;
    __syncthreads();
    // CSR meta (packed) + convert hist -> cursors
    for (int i = tid; i < 1024; i += 512) {
        int bucket = (bin << 10) + i;
        if (bucket < MM)
            meta[bucket] = make_uint2((unsigned)(bin * BCAP_PAD + start[i]),
                                      (unsigned)hist[i]);
        hist[i] = start[i];
    }
    __syncthreads();
    int* sb = sorted + (size_t)bin * BCAP_PAD;
    // scatter srcs bucket-contiguous (writes confined to L2-resident window)
    for (int i = tid; i < cnt; i += 512) {
        int w = bd[i];
        int pos = atomicAdd(&hist[w >> 17], 1);
        if (pos < BCAP_PAD) sb[pos] = w & 0x1ffff;
    }
    __syncthreads();
    // pad fill: positions [start+d, start+padlen) get zero-row index NN
    for (int i = tid; i < 1024; i += 512) {
        int s0 = start[i];
        int d = hist[i] - s0;              // final cursor - start = raw count
        int pl = (d + 3) & ~3;
        for (int p = s0 + d; p < s0 + pl; ++p)
            if (p < BCAP_PAD) sb[p] = NN;
    }
}

// ---------------- gather-aggregate: 8 buckets/wave, pad4, NT loads ----------------
// AT CEILING: logical gather ~416 MB / 65 us = 6.4 TB/s combined cache delivery.
__global__ __launch_bounds__(256) void aggregate_kernel(
    const ushort* __restrict__ xh, const int* __restrict__ sorted,
    const uint2* __restrict__ meta, ushort* __restrict__ aggh)
{
    int grp = blockIdx.x * 4 + (threadIdx.x >> 6);   // group of 8 buckets; grid = MM/32
    int lane = threadIdx.x & 63;
    int bid0 = grp * 8;                              // 8 consecutive buckets, same bin
    uintx2 m = __builtin_nontemporal_load(
        (const uintx2*)meta + (bid0 + (lane & 7)));  // one load round for all 8 metas
    int st[8], dg[8];
    #pragma unroll
    for (int b = 0; b < 8; ++b) {
        st[b] = __builtin_amdgcn_readlane((int)m.x, b);
        dg[b] = __builtin_amdgcn_readlane((int)m.y, b);
    }
    int start0 = st[0];
    int L = (st[7] - start0) + ((dg[7] + 3) & ~3);   // combined padded length (mean ~52)
    const unsigned* xu = (const unsigned*)xh;
    float ax[8], ay[8];
    #pragma unroll
    for (int b = 0; b < 8; ++b) { ax[b] = 0.f; ay[b] = 0.f; }

    if (L <= 64) {                                   // ~97% of groups
        int sidx = __builtin_nontemporal_load(&sorted[start0 + lane]);
        #pragma unroll
        for (int b = 0; b < 8; ++b) {
            int off = st[b] - start0;
            int degp = (dg[b] + 3) & ~3;
            for (int j = 0; j < degp; j += 4) {
                #pragma unroll
                for (int u = 0; u < 4; ++u) {
                    int sj = __builtin_amdgcn_readlane(sidx, off + j + u); // SGPR row idx
                    unsigned v = xu[(size_t)sj * 64 + lane];               // SGPR-base gather
                    ax[b] += bflo(v);
                    ay[b] += bfhi(v);
                }
            }
        }
    } else {                                         // fallback: uniform-addr loads
        #pragma unroll
        for (int b = 0; b < 8; ++b) {
            const int* sb = sorted + st[b];
            int degp = (dg[b] + 3) & ~3;
            for (int j = 0; j < degp; j += 4) {
                #pragma unroll
                for (int u = 0; u < 4; ++u) {
                    int sj = sb[j + u];              // padded: always valid
                    unsigned v = xu[(size_t)sj * 64 + lane];
                    ax[b] += bflo(v);
                    ay[b] += bfhi(v);
                }
            }
        }
    }
    #pragma unroll
    for (int b = 0; b < 8; ++b) {
        int deg = dg[b];
        float sc = 1.0f / (float)(deg > 1 ? deg : 1);
        unsigned o = (unsigned)f2bf(ax[b] * sc) | ((unsigned)f2bf(ay[b] * sc) << 16);
        ((unsigned*)(aggh + (size_t)(bid0 + b) * DD))[lane] = o;   // plain store: L3-warm
    }
}

// ---------------- fused GEMM: out = relu([xh|agg]@QBt^T + cb) @ P2t^T + b2 ----------
// 512 threads / 8 waves (2x4): grid is only 782 blocks (~3/CU), so TLP comes from
// waves-per-block, not blocks-per-CU. Per-wave output 64x32. A and B software-
// pipelined (prefetch chunk c+1 into regs during chunk c's MFMA). LDS 36,864 B.
__global__ __launch_bounds__(512) void gemm_fused_kernel(
    const ushort* __restrict__ xh, const ushort* __restrict__ aggh,
    const ushort* __restrict__ QBt, const float* __restrict__ cb,
    const ushort* __restrict__ P2t, const float* __restrict__ b2,
    float* __restrict__ out)
{
    __shared__ ushort S[18432];                        // 36,864 B
    ushort (*As)[72]  = (ushort(*)[72])S;              // stage1 A  [128][72]
    ushort (*Bs)[72]  = (ushort(*)[72])(S + 9216);     // stage1 B  [128][72]
    ushort (*Hs)[136] = (ushort(*)[136])S;             // stage2 A  [128][136] (overlays)

    int tid = threadIdx.x;
    int n0 = blockIdx.x * 128;
    int wid = tid >> 6;            // 0..7
    int lane = tid & 63;
    int wr = wid >> 2;             // 0..1  (64-row half)
    int wc = wid & 3;              // 0..3  (32-col quarter)
    int lrow = lane & 15;
    int lk = (lane >> 4) * 8;

    f32x4 acc[4][2];
    #pragma unroll
    for (int i = 0; i < 4; ++i)
        #pragma unroll
        for (int j = 0; j < 2; ++j) acc[i][j] = (f32x4){0.f, 0.f, 0.f, 0.f};

    // register prefetch buffers: 2 x 16B each for A and B (512 threads cover 1024 slots)
    ushort8 ra[2], rb[2];
    auto loadA = [&](int c, ushort8* v) {
        int seg = c >> 1, kloc = (c & 1) * 64;
        const ushort* Abase = (seg == 0) ? xh : (aggh + (size_t)(seg - 1) * NN * DD);
        #pragma unroll
        for (int i = 0; i < 2; ++i) {
            int id = tid + i * 512;
            int row = id >> 3, s16 = id & 7;
            int grow = n0 + row;
            ushort8 t = {0, 0, 0, 0, 0, 0, 0, 0};
            if (grow < NN)
                t = *(const ushort8*)(Abase + (size_t)grow * DD + kloc + s16 * 8);
            v[i] = t;
        }
    };
    auto loadB = [&](int c, ushort8* v) {
        #pragma unroll
        for (int i = 0; i < 2; ++i) {
            int id = tid + i * 512;
            int n = id >> 3, s16 = id & 7;
            v[i] = *(const ushort8*)(QBt + (size_t)n * 512 + c * 64 + s16 * 8);
        }
    };

    loadA(0, ra);
    loadB(0, rb);

    for (int c = 0; c < 8; ++c) {
        if (c) __syncthreads();                // prev MFMA done reading As/Bs
        #pragma unroll
        for (int i = 0; i < 2; ++i) {
            int id = tid + i * 512;
            int row = id >> 3, s16 = id & 7;
            *(ushort8*)&As[row][s16 * 8] = ra[i];
            *(ushort8*)&Bs[row][s16 * 8] = rb[i];
        }
        if (c < 7) { loadA(c + 1, ra); loadB(c + 1, rb); }  // fly during barrier+MFMA
        __syncthreads();
        #pragma unroll
        for (int ks = 0; ks < 2; ++ks) {
            bf16x8 a[4], b[2];
            #pragma unroll
            for (int mi = 0; mi < 4; ++mi)
                a[mi] = *(const bf16x8*)&As[wr * 64 + mi * 16 + lrow][ks * 32 + lk];
            #pragma unroll
            for (int ni = 0; ni < 2; ++ni)
                b[ni] = *(const bf16x8*)&Bs[wc * 32 + ni * 16 + lrow][ks * 32 + lk];
            #pragma unroll
            for (int mi = 0; mi < 4; ++mi)
                #pragma unroll
                for (int ni = 0; ni < 2; ++ni)
                    acc[mi][ni] = __builtin_amdgcn_mfma_f32_16x16x32_bf16(
                        a[mi], b[ni], acc[mi][ni], 0, 0, 0);
        }
    }

    // stage2 B-fragments from global (L2-broadcast) — issue before the barrier
    bf16x8 pb[4][2];   // [ks][ni]
    #pragma unroll
    for (int ks = 0; ks < 4; ++ks)
        #pragma unroll
        for (int ni = 0; ni < 2; ++ni)
            pb[ks][ni] = *(const bf16x8*)(P2t +
                (size_t)(wc * 32 + ni * 16 + lrow) * DD + ks * 32 + lk);

    __syncthreads();   // all stage1 LDS reads done before repurposing as Hs

    // epilogue1: h = relu(acc + cb) -> Hs (bf16); C/D layout row=(lane>>4)*4+q, col=lane&15
    int crow = lane >> 4;
    int ccol = lane & 15;
    #pragma unroll
    for (int ni = 0; ni < 2; ++ni) {
        int gcol = wc * 32 + ni * 16 + ccol;
        float cv = cb[gcol];
        #pragma unroll
        for (int mi = 0; mi < 4; ++mi) {
            #pragma unroll
            for (int q = 0; q < 4; ++q) {
                float v = acc[mi][ni][q] + cv;
                v = v > 0.f ? v : 0.f;
                Hs[wr * 64 + mi * 16 + crow * 4 + q][gcol] = f2bf(v);
            }
        }
    }
    __syncthreads();

    f32x4 acc2[4][2];
    #pragma unroll
    for (int i = 0; i < 4; ++i)
        #pragma unroll
        for (int j = 0; j < 2; ++j) acc2[i][j] = (f32x4){0.f, 0.f, 0.f, 0.f};

    #pragma unroll
    for (int ks = 0; ks < 4; ++ks) {
        bf16x8 a[4];
        #pragma unroll
        for (int mi = 0; mi < 4; ++mi)
            a[mi] = *(const bf16x8*)&Hs[wr * 64 + mi * 16 + lrow][ks * 32 + lk];
        #pragma unroll
        for (int mi = 0; mi < 4; ++mi)
            #pragma unroll
            for (int ni = 0; ni < 2; ++ni)
                acc2[mi][ni] = __builtin_amdgcn_mfma_f32_16x16x32_bf16(
                    a[mi], pb[ks][ni], acc2[mi][ni], 0, 0, 0);
    }

    #pragma unroll
    for (int ni = 0; ni < 2; ++ni) {
        int gcol = wc * 32 + ni * 16 + ccol;
        float bv = b2[gcol];
        #pragma unroll
        for (int mi = 0; mi < 4; ++mi) {
            #pragma unroll
            for (int q = 0; q < 4; ++q) {
                int gr = n0 + wr * 64 + mi * 16 + crow * 4 + q;
                if (gr < NN)
                    __builtin_nontemporal_store(acc2[mi][ni][q] + bv,
                                                &out[(size_t)gr * DD + gcol]);
            }
        }
    }
}

extern "C" void kernel_launch(void* const* d_in, const int* in_sizes, int n_in,
                              void* d_out, int out_size, void* d_ws, size_t ws_size,
                              hipStream_t stream) {
    const float* x  = (const float*)d_in[0];
    const int*   e0 = (const int*)d_in[1];
    const int*   e1 = (const int*)d_in[2];
    const int*   e2 = (const int*)d_in[3];
    const float* Wl = (const float*)d_in[4];
    const float* bl = (const float*)d_in[5];
    const float* Wr = (const float*)d_in[6];
    const float* P1 = (const float*)d_in[7];
    const float* b1 = (const float*)d_in[8];
    const float* P2 = (const float*)d_in[9];
    const float* b2 = (const float*)d_in[10];
    float* out = (float*)d_out;

    // ws layout (~122 MB)
    ushort* xh       = (ushort*)d_ws;                     // (N+1)*D    (25.6 MB; row N = zeros)
    ushort* aggh     = xh + (size_t)(NN + 1) * DD;        // R*N*D      (76.8 MB)
    ushort* QBt      = aggh + (size_t)RR * NN * DD;       // 128*512
    ushort* P2t      = QBt + (size_t)128 * 512;           // 128*128
    float*  cb       = (float*)(P2t + (size_t)DD * DD);   // D
    int*    g_cursor = (int*)(cb + DD);                   // NBIN
    int*    g_bindat = g_cursor + NBIN;                   // NBIN*BCAP_RAW (7.2 MB)
    int*    sorted   = g_bindat + (size_t)NBIN * BCAP_RAW;// NBIN*BCAP_PAD + 64 slack (9.6 MB)
    uint2*  meta     = (uint2*)(sorted + (size_t)NBIN * BCAP_PAD + 64);  // MM uint2

    (void)hipMemsetAsync(g_cursor, 0, NBIN * sizeof(int), stream);

    prep_kernel<<<ABLOCKS + TBLOCKS + PBLOCKS, 256, 0, stream>>>(
        e0, e1, e2, g_cursor, g_bindat, x, xh,
        Wl, Wr, P1, b1, bl, P2, QBt, P2t, cb);

    sort_kernel<<<NBIN, 512, 0, stream>>>(g_cursor, g_bindat, sorted, meta);

    aggregate_kernel<<<MM / 32, 256, 0, stream>>>(xh, sorted, meta, aggh);

    int gblocks = (NN + 127) / 128;
    gemm_fused_kernel<<<gblocks, 512, 0, stream>>>(xh, aggh, QBt, cb, P2t, b2, out);
}